// Round 3
// baseline (2467.502 us; speedup 1.0000x reference)
//
#include <hip/hip_runtime.h>
#include <hip/hip_bf16.h>
#include <math.h>

typedef __bf16 bf16;
typedef __bf16 bf16x4 __attribute__((ext_vector_type(4)));
typedef __bf16 bf16x8 __attribute__((ext_vector_type(8)));
typedef float f32x4 __attribute__((ext_vector_type(4)));
typedef _Float16 f16;
typedef _Float16 f16x2 __attribute__((ext_vector_type(2)));
typedef _Float16 f16x4 __attribute__((ext_vector_type(4)));
typedef _Float16 f16x8 __attribute__((ext_vector_type(8)));

#define BB 64
#define NN 49
#define CENC 2048
#define SS 26
#define NSTEP 25
#define VV 10000
#define EE 512
#define HH 512
#define AAT 512
#define ALPHA_OFF (BB*NSTEP*VV)

// T16 swizzled layout for MFMA operands: matrix M[R x K] (R%16==0, K%32==0)
// element (r,k) at sw[((rt*KC + kc)*64 + lane)*8 + j]
//   rt=r/16, kc=k/32, lane=((k%32)/8)*16 + (r%16), j=k%8, KC=K/32

struct Wks {
  float att1[BB*NN*AAT];            // fp32 row-major [3136][512] (benc folded)
  float h0[BB*HH];                  // initial state (k_init output)
  float c0[BB*HH];
  float embg[NSTEP*BB*4*HH];        // xemb @ Wih_e^T + bih + bhh  [1600][2048]
  union {                           // fg16 live k_enc..k_steps; w.* before/after
    f16 fg16[BB*NN*4*HH];           // feat @ Wih_c^T  [3136][2048] fp16
    struct {
      bf16 Wfcn_hi[10048*HH];       // T16 (R=10000 pad 10048,K=512) — after loop
      bf16 Winh_hi[HH*CENC];        // T16 (R=512,K=2048) — dead after k_init
      bf16 Winc_hi[HH*CENC];
    } w;
  } u;
  f16 Wcomb[2560*512];              // fp16 row-major: rows 0..511 Wdec, 512.. Whh
  bf16 mean_hi[BB*CENC];            // T16 (R=64,K=2048)
  bf16 mean_lo[BB*CENC];
  bf16 xemb_hi[NSTEP*BB*EE];        // T16 (R=1600,K=512), row=s*64+b
  bf16 xemb_lo[NSTEP*BB*EE];
  bf16 hist_hi[NSTEP*BB*HH];        // T16 (R=1600,K=512), row=s*64+b
  bf16 hist_lo[NSTEP*BB*HH];
  bf16 Wih_hi[4*HH*(EE+CENC)];      // T16 (R=2048,K=2560,KC=80)
  bf16 Wih_lo[4*HH*(EE+CENC)];
  bf16 Wenc_hi[AAT*CENC];           // T16 (R=512,K=2048,KC=64)
};

__device__ inline bf16x8 ldb8(const bf16* p){ return *(const bf16x8*)p; }
__device__ inline f32x4 mfma16(bf16x8 a, bf16x8 b, f32x4 c){
  return __builtin_amdgcn_mfma_f32_16x16x32_bf16(a, b, c, 0, 0, 0);
}
__device__ inline float sigm(float x){ return 1.0f/(1.0f+expf(-x)); }

__device__ inline float fdot2(f16x2 a, f16x2 b, float c){
#if __has_builtin(__builtin_amdgcn_fdot2)
  return __builtin_amdgcn_fdot2(a, b, c, false);
#else
  return c + (float)a[0]*(float)b[0] + (float)a[1]*(float)b[1];
#endif
}

__device__ inline void split8(const float* p, bf16x8& hi, bf16x8& lo){
  float4 v0 = *(const float4*)p;
  float4 v1 = *(const float4*)(p+4);
  float v[8] = {v0.x,v0.y,v0.z,v0.w,v1.x,v1.y,v1.z,v1.w};
  #pragma unroll
  for (int j=0;j<8;j++){ bf16 h=(bf16)v[j]; hi[j]=h; lo[j]=(bf16)(v[j]-(float)h); }
}

// direct-to-LDS 16B per lane
__device__ inline void gll16(const bf16* g, bf16* l){
  __builtin_amdgcn_global_load_lds(
      (const __attribute__((address_space(1))) void*)g,
      (__attribute__((address_space(3))) void*)l, 16, 0, 0);
}

// ---------------- fp32 -> fp16 convert (row-major) ---------------------------------
__global__ __launch_bounds__(256) void k_cvt16(const float* __restrict__ src,
    f16* __restrict__ dst, int n4){
  int i = blockIdx.x*256 + threadIdx.x;
  if (i >= n4) return;
  float4 v = ((const float4*)src)[i];
  f16x4 o = {(f16)v.x, (f16)v.y, (f16)v.z, (f16)v.w};
  *(f16x4*)(dst + (size_t)i*4) = o;
}

// ---------------- fp32 row-major -> T16 swizzle (hi + optional lo) -----------------
__global__ __launch_bounds__(256) void k_cvt_sw(const float* __restrict__ src,
    bf16* __restrict__ hi, bf16* __restrict__ lo, int R, int K, int ntile){
  int g = blockIdx.x*256 + threadIdx.x;
  if (g >= ntile*64) return;
  int tile = g>>6, lane = g&63;
  int KC = K>>5;
  int rt = tile/KC, kc = tile - rt*KC;
  int r = rt*16 + (lane&15);
  if (r >= R) r = R-1;
  int k = kc*32 + (lane>>4)*8;
  bf16x8 hv, lv;
  split8(src + (size_t)r*K + k, hv, lv);
  *(bf16x8*)(hi + (size_t)g*8) = hv;
  if (lo) *(bf16x8*)(lo + (size_t)g*8) = lv;
}

// ---------------- gather caption embeddings -> T16 hi/lo ---------------------------
__global__ __launch_bounds__(256) void k_emb(const int* __restrict__ caps,
    const float* __restrict__ emb, Wks* __restrict__ ws){
  int g = blockIdx.x*256 + threadIdx.x;
  if (g >= 1600*64) return;
  int tile = g>>6, lane = g&63;
  int rt = tile>>4, kc = tile&15;
  int r = rt*16 + (lane&15);
  int s = r>>6, b = r&63;
  int k = kc*32 + (lane>>4)*8;
  int cap = caps[b*SS + s];
  bf16x8 hv, lv;
  split8(emb + (size_t)cap*EE + k, hv, lv);
  *(bf16x8*)(ws->xemb_hi + (size_t)g*8) = hv;
  *(bf16x8*)(ws->xemb_lo + (size_t)g*8) = lv;
}

// ---------------- mean over N=49 pixels -> T16 hi/lo -------------------------------
__global__ __launch_bounds__(256) void k_mean(const float* __restrict__ feat, Wks* __restrict__ ws){
  int idx = blockIdx.x*256 + threadIdx.x;
  int b = idx >> 11, ch = idx & 2047;
  const float* p = feat + (size_t)b*NN*CENC + ch;
  float s = 0.f;
  #pragma unroll
  for (int n=0;n<NN;n++) s += p[n*CENC];
  s *= (1.0f/49.0f);
  bf16 hi = (bf16)s;
  int off = (((b>>4)*64 + (ch>>5))*64 + ((ch&31)>>3)*16 + (b&15))*8 + (ch&7);
  ws->mean_hi[off] = hi;
  ws->mean_lo[off] = (bf16)(s - (float)hi);
}

// ---------------- h0/c0 init (T16 operands) ----------------------------------------
__global__ __launch_bounds__(256) void k_init(Wks* __restrict__ ws,
    const float* __restrict__ bh, const float* __restrict__ bc){
  int wid = threadIdx.x >> 6, lane = threadIdx.x & 63;
  int w = blockIdx.x*4 + wid;                // 0..63
  int mat = w >> 5, nt = w & 31;
  int lane15 = lane & 15, quad = lane >> 4;
  const bf16* Wm = mat ? ws->u.w.Winc_hi : ws->u.w.Winh_hi;
  const float* bm = mat ? bc : bh;
  int col = nt*16 + lane15;
  f32x4 acc[4] = {};
  for (int kc=0; kc<64; kc++){
    bf16x8 bfr = ldb8(Wm + (((size_t)nt*64 + kc)*64 + lane)*8);
    #pragma unroll
    for (int t=0;t<4;t++){
      acc[t] = mfma16(ldb8(ws->mean_hi + (((size_t)t*64 + kc)*64 + lane)*8), bfr, acc[t]);
      acc[t] = mfma16(ldb8(ws->mean_lo + (((size_t)t*64 + kc)*64 + lane)*8), bfr, acc[t]);
    }
  }
  float bias = bm[col];
  #pragma unroll
  for (int t=0;t<4;t++){
    #pragma unroll
    for (int r=0;r<4;r++){
      int b = t*16 + quad*4 + r;
      float v = acc[t][r] + bias;
      if (mat == 0) ws->h0[b*HH + col] = v;
      else          ws->c0[b*HH + col] = v;
    }
  }
}

// ---------------- embgates = xemb @ Wih_e^T + bih + bhh  [1600][2048] --------------
__global__ __launch_bounds__(256) void k_embg(Wks* __restrict__ ws,
    const float* __restrict__ bih, const float* __restrict__ bhh){
  int wid = threadIdx.x>>6, lane = threadIdx.x&63;
  int w = blockIdx.x*4 + wid;                // 3200 waves: w = nt*25 + mtg
  int nt = w/25, mtg = w - nt*25;
  int lane15 = lane&15, quad = lane>>4;
  f32x4 acc[4] = {};
  for (int kc=0; kc<16; kc++){
    bf16x8 wh = ldb8(ws->Wih_hi + (((size_t)nt*80 + kc)*64 + lane)*8);
    bf16x8 wl = ldb8(ws->Wih_lo + (((size_t)nt*80 + kc)*64 + lane)*8);
    #pragma unroll
    for (int i=0;i<4;i++){
      int rt = mtg*4 + i;
      bf16x8 ah = ldb8(ws->xemb_hi + (((size_t)rt*16 + kc)*64 + lane)*8);
      bf16x8 al = ldb8(ws->xemb_lo + (((size_t)rt*16 + kc)*64 + lane)*8);
      acc[i] = mfma16(ah, wh, acc[i]);
      acc[i] = mfma16(al, wh, acc[i]);
      acc[i] = mfma16(ah, wl, acc[i]);
    }
  }
  int col = nt*16 + lane15;
  float bias = bih[col] + bhh[col];
  #pragma unroll
  for (int i=0;i<4;i++){
    #pragma unroll
    for (int r=0;r<4;r++){
      int row = (mtg*4+i)*16 + quad*4 + r;   // row = s*64 + b
      ws->embg[(size_t)row*(4*HH) + col] = acc[i][r] + bias;
    }
  }
}

// ---------------- encoder GEMM: att1 + featgates in one pass over feat -------------
// XCD-chunked mb-major block order: each XCD's resident blocks share feat slices.
__global__ __launch_bounds__(256) void k_enc(const float* __restrict__ feat,
    const float* __restrict__ benc, Wks* __restrict__ ws)
{
  __shared__ bf16 sm[2][24*512];
  // bijective XCD swizzle over 980 wgs (q=122, r=4)
  int xcd = blockIdx.x & 7, idx = blockIdx.x >> 3;
  int wg = (xcd < 4) ? xcd*123 + idx : 4*123 + (xcd-4)*122 + idx;
  int mb = wg / 20, nb = wg % 20;
  int tid = threadIdx.x, wid = tid>>6, lane = tid&63;
  int lane15 = lane&15, quad = lane>>4;
  bool is_fg = (nb < 16);
  int rr = tid>>2, qo = tid&3;
  const float* arow = feat + (size_t)(mb*64 + rr)*CENC + qo*8;
  int a_ds = ((rr>>4)*2)*512 + (qo*16 + (rr&15))*8;

  f32x4 acc[8] = {};

  auto stageB = [&](int kc, int buf){
    if (is_fg){
      #pragma unroll
      for (int j=0;j<4;j++){
        int tt = wid*4 + j;
        int ntl = tt>>1;
        const bf16* src = ((tt&1) ? ws->Wih_lo : ws->Wih_hi)
            + (size_t)((nb*8 + ntl)*80 + 16 + kc)*512 + lane*8;
        gll16(src, &sm[buf][(8+tt)*512]);
      }
    } else {
      #pragma unroll
      for (int j=0;j<2;j++){
        int tt = wid*2 + j;
        const bf16* src = ws->Wenc_hi
            + (size_t)(((nb-16)*8 + tt)*64 + kc)*512 + lane*8;
        gll16(src, &sm[buf][(8+tt)*512]);
      }
    }
  };
  auto cvtwr = [&](int buf, float4 v0, float4 v1){
    float v[8] = {v0.x,v0.y,v0.z,v0.w,v1.x,v1.y,v1.z,v1.w};
    bf16x8 hv, lv;
    #pragma unroll
    for (int j=0;j<8;j++){ bf16 h=(bf16)v[j]; hv[j]=h; lv[j]=(bf16)(v[j]-(float)h); }
    *(bf16x8*)(&sm[buf][a_ds]) = hv;
    *(bf16x8*)(&sm[buf][a_ds+512]) = lv;
  };

  stageB(0, 0);
  { float4 v0 = *(const float4*)arow;
    float4 v1 = *(const float4*)(arow+4);
    cvtwr(0, v0, v1); }
  __syncthreads();

  for (int kc=0; kc<64; kc++){
    int cur = kc & 1;
    bool pf = (kc < 63);
    float4 v0, v1;
    if (pf){
      stageB(kc+1, cur^1);
      const float* p = arow + (kc+1)*32;
      v0 = *(const float4*)p; v1 = *(const float4*)(p+4);
    }
    const bf16* S = sm[cur];
    bf16x8 ah = ldb8(S + (wid*2)*512 + lane*8);
    bf16x8 al = ldb8(S + (wid*2+1)*512 + lane*8);
    if (is_fg){
      #pragma unroll
      for (int u=0;u<8;u++){
        bf16x8 wh = ldb8(S + (size_t)(8+u*2)*512 + lane*8);
        bf16x8 wl = ldb8(S + (size_t)(9+u*2)*512 + lane*8);
        acc[u] = mfma16(ah, wh, acc[u]);
        acc[u] = mfma16(al, wh, acc[u]);
        acc[u] = mfma16(ah, wl, acc[u]);
      }
    } else {
      #pragma unroll
      for (int u=0;u<8;u++){
        bf16x8 wh = ldb8(S + (size_t)(8+u)*512 + lane*8);
        acc[u] = mfma16(ah, wh, acc[u]);
        acc[u] = mfma16(al, wh, acc[u]);
      }
    }
    if (pf) cvtwr(cur^1, v0, v1);
    __syncthreads();
  }

  if (is_fg){
    #pragma unroll
    for (int u=0;u<8;u++){
      int col = nb*128 + u*16 + lane15;
      #pragma unroll
      for (int r=0;r<4;r++){
        int row = mb*64 + wid*16 + quad*4 + r;
        ws->u.fg16[(size_t)row*(4*HH) + col] = (f16)acc[u][r];
      }
    }
  } else {
    #pragma unroll
    for (int u=0;u<8;u++){
      int col = (nb-16)*128 + u*16 + lane15;
      float bias = benc[col];
      #pragma unroll
      for (int r=0;r<4;r++){
        int row = mb*64 + wid*16 + quad*4 + r;
        ws->att1[(size_t)row*AAT + col] = acc[u][r] + bias;
      }
    }
  }
}

// ---------------- persistent per-batch step loop (NO cross-block sync) -------------
// 64 blocks (one per b) x 1024 threads. All state block-local in LDS/regs.
// Per step: [att2 | hwhh] fp16 dot2 matvec -> e -> softmax -> gates(+fg sum) -> LSTM.
__global__ __launch_bounds__(1024) void k_steps(Wks* __restrict__ ws,
    const float* __restrict__ bdec, const float* __restrict__ Wfull,
    float* __restrict__ out)
{
  int b = blockIdx.x;
  int tid = threadIdx.x;
  int lane = tid & 63, wid = tid >> 6;
  __shared__ float att2_s[512];
  __shared__ float g_s[2048];
  __shared__ float c_s[512];
  __shared__ float wf_s[512];
  __shared__ float bd_s[512];
  __shared__ __align__(16) f16 h16_s[512];
  __shared__ float e_s[64];
  __shared__ float al_s[64];
  if (tid < 512){
    c_s[tid] = ws->c0[b*HH + tid];
    h16_s[tid] = (f16)ws->h0[b*HH + tid];
    wf_s[tid] = Wfull[tid];
    bd_s[tid] = bdec[tid];
  }
  __syncthreads();
  const f16* fg = ws->u.fg16 + (size_t)b*NN*(4*HH);
  int j0 = tid*2;
  const f16x8* w0 = (const f16x8*)(ws->Wcomb + (size_t)(512 + j0)*512);
  const f16x8* w1 = (const f16x8*)(ws->Wcomb + (size_t)(512 + j0 + 1)*512);
  const f16x8* wa = (const f16x8*)(ws->Wcomb + (size_t)tid*512);
  const f16x8* hp = (const f16x8*)h16_s;

  for (int t=0; t<NSTEP; t++){
    // ---- matvec: hwhh (2 rows/thread) + att2 (threads<512, 1 extra row) ----
    float a0 = 0.f, a1 = 0.f;
    if (tid < 512){
      float aa = 0.f;
      #pragma unroll 4
      for (int kk=0; kk<64; kk++){
        f16x8 hv = hp[kk];
        f16x8 v0 = w0[kk], v1 = w1[kk], va = wa[kk];
        #pragma unroll
        for (int p=0;p<4;p++){
          f16x2 h2 = {hv[2*p], hv[2*p+1]};
          a0 = fdot2((f16x2){v0[2*p], v0[2*p+1]}, h2, a0);
          a1 = fdot2((f16x2){v1[2*p], v1[2*p+1]}, h2, a1);
          aa = fdot2((f16x2){va[2*p], va[2*p+1]}, h2, aa);
        }
      }
      att2_s[tid] = aa + bd_s[tid];
    } else {
      #pragma unroll 4
      for (int kk=0; kk<64; kk++){
        f16x8 hv = hp[kk];
        f16x8 v0 = w0[kk], v1 = w1[kk];
        #pragma unroll
        for (int p=0;p<4;p++){
          f16x2 h2 = {hv[2*p], hv[2*p+1]};
          a0 = fdot2((f16x2){v0[2*p], v0[2*p+1]}, h2, a0);
          a1 = fdot2((f16x2){v1[2*p], v1[2*p+1]}, h2, a1);
        }
      }
    }
    __syncthreads();
    // ---- e[n] = relu(att1 + att2) . wf  (att1 from global, L2-warm) ----
    for (int n = wid; n < NN; n += 16){
      const float* at1 = ws->att1 + ((size_t)(b*NN + n))*AAT + lane*8;
      float4 p0 = *(const float4*)at1;
      float4 p1 = *(const float4*)(at1+4);
      float av[8] = {p0.x,p0.y,p0.z,p0.w,p1.x,p1.y,p1.z,p1.w};
      float s = 0.f;
      #pragma unroll
      for (int j=0;j<8;j++){
        float v = av[j] + att2_s[lane*8+j];
        v = fmaxf(v, 0.0f);
        s += v * wf_s[lane*8+j];
      }
      #pragma unroll
      for (int off=32; off; off>>=1) s += __shfl_xor(s, off, 64);
      if (lane==0) e_s[n] = s;
    }
    __syncthreads();
    // ---- softmax (wave 0) ----
    if (wid == 0){
      float e = (lane < NN) ? e_s[lane] : -1e30f;
      float m = e;
      #pragma unroll
      for (int off=32; off; off>>=1) m = fmaxf(m, __shfl_xor(m, off, 64));
      float p = (lane < NN) ? expf(e - m) : 0.0f;
      float su = p;
      #pragma unroll
      for (int off=32; off; off>>=1) su += __shfl_xor(su, off, 64);
      float al = p / su;
      if (lane < NN){
        al_s[lane] = al;
        out[ALPHA_OFF + (size_t)(b*NSTEP + t)*NN + lane] = al;
      }
    }
    __syncthreads();
    // ---- gates = hwhh + embg + sum_n alpha*fg16 ----
    {
      float2 eg = *(const float2*)&ws->embg[((size_t)(t*64 + b))*(4*HH) + j0];
      float g0 = a0 + eg.x;
      float g1 = a1 + eg.y;
      const f16x2* fp = (const f16x2*)fg + tid;
      #pragma unroll 7
      for (int n=0;n<NN;n++){
        float a = al_s[n];
        f16x2 v = fp[(size_t)n*1024];
        g0 += a * (float)v[0];
        g1 += a * (float)v[1];
      }
      g_s[j0] = g0;
      g_s[j0+1] = g1;
    }
    __syncthreads();
    // ---- LSTM pointwise + state/hist update ----
    if (tid < 512){
      float iv = g_s[tid], fv = g_s[tid+512], gv = g_s[tid+1024], ov = g_s[tid+1536];
      float co = c_s[tid];
      float cn = sigm(fv)*co + sigm(iv)*tanhf(gv);
      float hn = sigm(ov)*tanhf(cn);
      c_s[tid] = cn;
      h16_s[tid] = (f16)hn;
      bf16 hi_ = (bf16)hn;
      bf16 lo_ = (bf16)(hn - (float)hi_);
      int jj = tid;
      int kc = jj>>5, lane_w = ((jj&31)>>3)*16 + (b&15), j8 = jj&7;
      size_t offhist = ((((size_t)t*4 + (b>>4))*16 + kc)*64 + lane_w)*8 + j8;
      ws->hist_hi[offhist] = hi_;
      ws->hist_lo[offhist] = lo_;
    }
    __syncthreads();
  }
}

// ---------------- final pred GEMM: [1600 x 10000] = hist @ Wfcn^T (T16) ------------
__global__ __launch_bounds__(256) void k_pred(Wks* __restrict__ ws,
    const float* __restrict__ bfcn, float* __restrict__ out)
{
  int wid = threadIdx.x>>6, lane = threadIdx.x&63;
  int mt = blockIdx.y*4 + wid;
  int nt = blockIdx.x;
  if (mt >= NSTEP) return;
  int lane15 = lane&15, quad = lane>>4;
  int n0 = nt*64;
  f32x4 acc[4][4] = {};
  for (int kc=0; kc<16; kc++){
    bf16x8 a_hi[4], a_lo[4], bw[4];
    #pragma unroll
    for (int i=0;i<4;i++){
      a_hi[i] = ldb8(ws->hist_hi + (((size_t)(mt*4+i)*16 + kc)*64 + lane)*8);
      a_lo[i] = ldb8(ws->hist_lo + (((size_t)(mt*4+i)*16 + kc)*64 + lane)*8);
    }
    #pragma unroll
    for (int u=0;u<4;u++)
      bw[u] = ldb8(ws->u.w.Wfcn_hi + (((size_t)(nt*4+u)*16 + kc)*64 + lane)*8);
    #pragma unroll
    for (int u=0;u<4;u++){
      #pragma unroll
      for (int i=0;i<4;i++){
        acc[u][i] = mfma16(a_hi[i], bw[u], acc[u][i]);
        acc[u][i] = mfma16(a_lo[i], bw[u], acc[u][i]);
      }
    }
  }
  #pragma unroll
  for (int u=0;u<4;u++){
    int vc = n0 + u*16 + lane15;
    if (vc < VV){
      float bias = bfcn[vc];
      #pragma unroll
      for (int i=0;i<4;i++){
        #pragma unroll
        for (int r=0;r<4;r++){
          int row = mt*64 + i*16 + quad*4 + r;   // row = s*64 + b
          int sstep = row >> 6, bidx = row & 63;
          out[(size_t)(bidx*NSTEP + sstep)*VV + vc] = acc[u][i][r] + bias;
        }
      }
    }
  }
}

extern "C" void kernel_launch(void* const* d_in, const int* in_sizes, int n_in,
                              void* d_out, int out_size, void* d_ws, size_t ws_size,
                              hipStream_t stream)
{
  const float* feat = (const float*)d_in[0];
  const int*   caps = (const int*)d_in[1];
  const float* emb  = (const float*)d_in[2];
  const float* Wih  = (const float*)d_in[3];
  const float* bih  = (const float*)d_in[4];
  const float* Whh  = (const float*)d_in[5];
  const float* bhh  = (const float*)d_in[6];
  const float* Wenc = (const float*)d_in[7];
  const float* benc = (const float*)d_in[8];
  const float* Wdec = (const float*)d_in[9];
  const float* bdec = (const float*)d_in[10];
  const float* Wfull= (const float*)d_in[11];
  const float* bfull= (const float*)d_in[12];
  const float* Winh = (const float*)d_in[13];
  const float* binh = (const float*)d_in[14];
  const float* Winc = (const float*)d_in[15];
  const float* binc = (const float*)d_in[16];
  const float* Wfcn = (const float*)d_in[17];
  const float* bfcn = (const float*)d_in[18];
  float* out = (float*)d_out;
  Wks* ws = (Wks*)d_ws;
  if (ws_size < sizeof(Wks)) return;
  (void)bfull;

  #define SW(src, hi, lo, R, K) do { int nt_ = ((R+15)/16)*((K)/32); \
    hipLaunchKernelGGL(k_cvt_sw, dim3((nt_*64+255)/256), dim3(256), 0, stream, \
        src, hi, lo, R, K, nt_); } while(0)
  SW(Wih,  ws->Wih_hi,  ws->Wih_lo,  2048, 2560);
  SW(Wenc, ws->Wenc_hi, (bf16*)nullptr, 512, 2048);
  SW(Winh, ws->u.w.Winh_hi, (bf16*)nullptr, 512, 2048);
  SW(Winc, ws->u.w.Winc_hi, (bf16*)nullptr, 512, 2048);
  // Wcomb fp16: rows 0..511 = Wdec, rows 512..2559 = Whh
  hipLaunchKernelGGL(k_cvt16, dim3((AAT*HH/4+255)/256), dim3(256), 0, stream,
      Wdec, ws->Wcomb, AAT*HH/4);
  hipLaunchKernelGGL(k_cvt16, dim3((4*HH*HH/4+255)/256), dim3(256), 0, stream,
      Whh, ws->Wcomb + (size_t)512*512, 4*HH*HH/4);
  hipLaunchKernelGGL(k_emb, dim3(400), dim3(256), 0, stream, caps, emb, ws);
  hipLaunchKernelGGL(k_mean, dim3(512), dim3(256), 0, stream, feat, ws);
  hipLaunchKernelGGL(k_init, dim3(16), dim3(256), 0, stream, ws, binh, binc);
  hipLaunchKernelGGL(k_embg, dim3(800), dim3(256), 0, stream, ws, bih, bhh);
  hipLaunchKernelGGL(k_enc, dim3(980), dim3(256), 0, stream, feat, benc, ws);
  hipLaunchKernelGGL(k_steps, dim3(64), dim3(1024), 0, stream, ws, bdec, Wfull, out);
  // fg16 dead now: reuse its space for the Wfcn swizzle, then pred
  SW(Wfcn, ws->u.w.Wfcn_hi, (bf16*)nullptr, 10000, 512);
  #undef SW
  hipLaunchKernelGGL(k_pred, dim3(157, 7), dim3(256), 0, stream, ws, bfcn, out);
}

// Round 4
// 1846.780 us; speedup vs baseline: 1.3361x; 1.3361x over previous
//
#include <hip/hip_runtime.h>
#include <hip/hip_bf16.h>
#include <math.h>

typedef __bf16 bf16;
typedef __bf16 bf16x4 __attribute__((ext_vector_type(4)));
typedef __bf16 bf16x8 __attribute__((ext_vector_type(8)));
typedef float f32x4 __attribute__((ext_vector_type(4)));
typedef _Float16 f16;
typedef _Float16 f16x4 __attribute__((ext_vector_type(4)));
typedef _Float16 f16x8 __attribute__((ext_vector_type(8)));

#define BB 64
#define NN 49
#define CENC 2048
#define SS 26
#define NSTEP 25
#define VV 10000
#define EE 512
#define HH 512
#define AAT 512
#define ALPHA_OFF (BB*NSTEP*VV)
#define NPROD 80
#define NCONS 128

// T16 swizzled layout for MFMA operands: matrix M[R x K] (R%16==0, K%32==0)
// element (r,k) at sw[((rt*KC + kc)*64 + lane)*8 + j]
//   rt=r/16, kc=k/32, lane=((k%32)/8)*16 + (r%16), j=k%8, KC=K/32

struct Wks {
  unsigned int flagP; unsigned int _p0[31];   // producers add 1/step (80/step)
  unsigned int flagH; unsigned int _p1[31];   // consumers add 1/step (128/step)
  f16  att1_16[BB*NN*AAT];          // fp16 row-major [3136][512], benc folded
  float c0[BB*HH];                  // initial cell state
  f16  h16t[BB*HH];                 // h state, fp16 T16 (R=64,K=512,KC=16)
  float hw[2560*64];                // producer out [col][b]: cols 0..2047 hwhh, 2048.. att2(raw)
  float embg[NSTEP*BB*4*HH];        // xemb @ Wih_e^T + bih + bhh  [1600][2048]
  union {                           // fg16 live k_enc..k_steps; w.* before/after
    f16 fg16[BB*NN*4*HH];           // feat @ Wih_c^T  [3136][2048] fp16
    struct {
      bf16 Wfcn_hi[10048*HH];       // T16 (R=10000 pad 10048,K=512) — after loop
      bf16 Winh_hi[HH*CENC];        // T16 (R=512,K=2048) — dead after k_init
      bf16 Winc_hi[HH*CENC];
    } w;
  } u;
  f16  Wcomb16[2560*HH];            // fp16 T16 (R=2560,K=512): rows 0..2047 Whh, 2048.. Wdec
  bf16 mean_hi[BB*CENC];            // T16 (R=64,K=2048)
  bf16 mean_lo[BB*CENC];
  bf16 xemb_hi[NSTEP*BB*EE];        // T16 (R=1600,K=512), row=s*64+b
  bf16 xemb_lo[NSTEP*BB*EE];
  bf16 hist_hi[NSTEP*BB*HH];        // T16 (R=1600,K=512), row=s*64+b
  bf16 hist_lo[NSTEP*BB*HH];
  bf16 Wih_hi[4*HH*(EE+CENC)];      // T16 (R=2048,K=2560,KC=80)
  bf16 Wih_lo[4*HH*(EE+CENC)];
  bf16 Wenc_hi[AAT*CENC];           // T16 (R=512,K=2048,KC=64)
};

__device__ inline bf16x8 ldb8(const bf16* p){ return *(const bf16x8*)p; }
__device__ inline f32x4 mfma16(bf16x8 a, bf16x8 b, f32x4 c){
  return __builtin_amdgcn_mfma_f32_16x16x32_bf16(a, b, c, 0, 0, 0);
}
__device__ inline f32x4 mfma16f(f16x8 a, f16x8 b, f32x4 c){
  return __builtin_amdgcn_mfma_f32_16x16x32_f16(a, b, c, 0, 0, 0);
}
__device__ inline float sigm(float x){ return 1.0f/(1.0f+expf(-x)); }

__device__ inline void split8(const float* p, bf16x8& hi, bf16x8& lo){
  float4 v0 = *(const float4*)p;
  float4 v1 = *(const float4*)(p+4);
  float v[8] = {v0.x,v0.y,v0.z,v0.w,v1.x,v1.y,v1.z,v1.w};
  #pragma unroll
  for (int j=0;j<8;j++){ bf16 h=(bf16)v[j]; hi[j]=h; lo[j]=(bf16)(v[j]-(float)h); }
}

// direct-to-LDS 16B per lane
__device__ inline void gll16(const bf16* g, bf16* l){
  __builtin_amdgcn_global_load_lds(
      (const __attribute__((address_space(1))) void*)g,
      (__attribute__((address_space(3))) void*)l, 16, 0, 0);
}

// ---------------- fp32 row-major -> T16 swizzle bf16 (hi + optional lo) ------------
__global__ __launch_bounds__(256) void k_cvt_sw(const float* __restrict__ src,
    bf16* __restrict__ hi, bf16* __restrict__ lo, int R, int K, int ntile){
  int g = blockIdx.x*256 + threadIdx.x;
  if (g >= ntile*64) return;
  int tile = g>>6, lane = g&63;
  int KC = K>>5;
  int rt = tile/KC, kc = tile - rt*KC;
  int r = rt*16 + (lane&15);
  if (r >= R) r = R-1;
  int k = kc*32 + (lane>>4)*8;
  bf16x8 hv, lv;
  split8(src + (size_t)r*K + k, hv, lv);
  *(bf16x8*)(hi + (size_t)g*8) = hv;
  if (lo) *(bf16x8*)(lo + (size_t)g*8) = lv;
}

// ---------------- fp32 row-major -> T16 swizzle fp16 -------------------------------
__global__ __launch_bounds__(256) void k_cvt_sw16(const float* __restrict__ src,
    f16* __restrict__ dst, int R, int K, int ntile){
  int g = blockIdx.x*256 + threadIdx.x;
  if (g >= ntile*64) return;
  int tile = g>>6, lane = g&63;
  int KC = K>>5;
  int rt = tile/KC, kc = tile - rt*KC;
  int r = rt*16 + (lane&15);
  if (r >= R) r = R-1;
  int k = kc*32 + (lane>>4)*8;
  float4 v0 = *(const float4*)(src + (size_t)r*K + k);
  float4 v1 = *(const float4*)(src + (size_t)r*K + k + 4);
  float v[8] = {v0.x,v0.y,v0.z,v0.w,v1.x,v1.y,v1.z,v1.w};
  f16x8 hv;
  #pragma unroll
  for (int j=0;j<8;j++) hv[j] = (f16)v[j];
  *(f16x8*)(dst + (size_t)g*8) = hv;
}

// ---------------- gather caption embeddings -> T16 hi/lo ---------------------------
__global__ __launch_bounds__(256) void k_emb(const int* __restrict__ caps,
    const float* __restrict__ emb, Wks* __restrict__ ws){
  int g = blockIdx.x*256 + threadIdx.x;
  if (g >= 1600*64) return;
  int tile = g>>6, lane = g&63;
  int rt = tile>>4, kc = tile&15;
  int r = rt*16 + (lane&15);
  int s = r>>6, b = r&63;
  int k = kc*32 + (lane>>4)*8;
  int cap = caps[b*SS + s];
  bf16x8 hv, lv;
  split8(emb + (size_t)cap*EE + k, hv, lv);
  *(bf16x8*)(ws->xemb_hi + (size_t)g*8) = hv;
  *(bf16x8*)(ws->xemb_lo + (size_t)g*8) = lv;
}

// ---------------- mean over N=49 pixels -> T16 hi/lo -------------------------------
__global__ __launch_bounds__(256) void k_mean(const float* __restrict__ feat, Wks* __restrict__ ws){
  int idx = blockIdx.x*256 + threadIdx.x;
  int b = idx >> 11, ch = idx & 2047;
  const float* p = feat + (size_t)b*NN*CENC + ch;
  float s = 0.f;
  #pragma unroll
  for (int n=0;n<NN;n++) s += p[n*CENC];
  s *= (1.0f/49.0f);
  bf16 hi = (bf16)s;
  int off = (((b>>4)*64 + (ch>>5))*64 + ((ch&31)>>3)*16 + (b&15))*8 + (ch&7);
  ws->mean_hi[off] = hi;
  ws->mean_lo[off] = (bf16)(s - (float)hi);
}

// ---------------- h0/c0 init (T16 operands); also zero flags -----------------------
__global__ __launch_bounds__(256) void k_init(Wks* __restrict__ ws,
    const float* __restrict__ bh, const float* __restrict__ bc){
  if (blockIdx.x == 0 && threadIdx.x == 0){ ws->flagP = 0u; ws->flagH = 0u; }
  int wid = threadIdx.x >> 6, lane = threadIdx.x & 63;
  int w = blockIdx.x*4 + wid;                // 0..63
  int mat = w >> 5, nt = w & 31;
  int lane15 = lane & 15, quad = lane >> 4;
  const bf16* Wm = mat ? ws->u.w.Winc_hi : ws->u.w.Winh_hi;
  const float* bm = mat ? bc : bh;
  int col = nt*16 + lane15;
  f32x4 acc[4] = {};
  for (int kc=0; kc<64; kc++){
    bf16x8 bfr = ldb8(Wm + (((size_t)nt*64 + kc)*64 + lane)*8);
    #pragma unroll
    for (int t=0;t<4;t++){
      acc[t] = mfma16(ldb8(ws->mean_hi + (((size_t)t*64 + kc)*64 + lane)*8), bfr, acc[t]);
      acc[t] = mfma16(ldb8(ws->mean_lo + (((size_t)t*64 + kc)*64 + lane)*8), bfr, acc[t]);
    }
  }
  float bias = bm[col];
  #pragma unroll
  for (int t=0;t<4;t++){
    #pragma unroll
    for (int r=0;r<4;r++){
      int b = t*16 + quad*4 + r;
      float v = acc[t][r] + bias;
      if (mat == 0){
        int kc2 = col>>5, lane_w = ((col&31)>>3)*16 + (b&15), j8 = col&7;
        ws->h16t[(((b>>4)*16 + kc2)*64 + lane_w)*8 + j8] = (f16)v;
      } else {
        ws->c0[b*HH + col] = v;
      }
    }
  }
}

// ---------------- embgates = xemb @ Wih_e^T + bih + bhh  [1600][2048] --------------
__global__ __launch_bounds__(256) void k_embg(Wks* __restrict__ ws,
    const float* __restrict__ bih, const float* __restrict__ bhh){
  int wid = threadIdx.x>>6, lane = threadIdx.x&63;
  int w = blockIdx.x*4 + wid;                // 3200 waves: w = nt*25 + mtg
  int nt = w/25, mtg = w - nt*25;
  int lane15 = lane&15, quad = lane>>4;
  f32x4 acc[4] = {};
  for (int kc=0; kc<16; kc++){
    bf16x8 wh = ldb8(ws->Wih_hi + (((size_t)nt*80 + kc)*64 + lane)*8);
    bf16x8 wl = ldb8(ws->Wih_lo + (((size_t)nt*80 + kc)*64 + lane)*8);
    #pragma unroll
    for (int i=0;i<4;i++){
      int rt = mtg*4 + i;
      bf16x8 ah = ldb8(ws->xemb_hi + (((size_t)rt*16 + kc)*64 + lane)*8);
      bf16x8 al = ldb8(ws->xemb_lo + (((size_t)rt*16 + kc)*64 + lane)*8);
      acc[i] = mfma16(ah, wh, acc[i]);
      acc[i] = mfma16(al, wh, acc[i]);
      acc[i] = mfma16(ah, wl, acc[i]);
    }
  }
  int col = nt*16 + lane15;
  float bias = bih[col] + bhh[col];
  #pragma unroll
  for (int i=0;i<4;i++){
    #pragma unroll
    for (int r=0;r<4;r++){
      int row = (mtg*4+i)*16 + quad*4 + r;   // row = s*64 + b
      ws->embg[(size_t)row*(4*HH) + col] = acc[i][r] + bias;
    }
  }
}

// ---------------- encoder GEMM: att1(f16) + featgates(f16) in one pass over feat ---
__global__ __launch_bounds__(256) void k_enc(const float* __restrict__ feat,
    const float* __restrict__ benc, Wks* __restrict__ ws)
{
  __shared__ bf16 sm[2][24*512];
  // bijective XCD swizzle over 980 wgs (q=122, r=4), mb-major within XCD chunk
  int xcd = blockIdx.x & 7, idx = blockIdx.x >> 3;
  int wg = (xcd < 4) ? xcd*123 + idx : 4*123 + (xcd-4)*122 + idx;
  int mb = wg / 20, nb = wg % 20;
  int tid = threadIdx.x, wid = tid>>6, lane = tid&63;
  int lane15 = lane&15, quad = lane>>4;
  bool is_fg = (nb < 16);
  int rr = tid>>2, qo = tid&3;
  const float* arow = feat + (size_t)(mb*64 + rr)*CENC + qo*8;
  int a_ds = ((rr>>4)*2)*512 + (qo*16 + (rr&15))*8;

  f32x4 acc[8] = {};

  auto stageB = [&](int kc, int buf){
    if (is_fg){
      #pragma unroll
      for (int j=0;j<4;j++){
        int tt = wid*4 + j;
        int ntl = tt>>1;
        const bf16* src = ((tt&1) ? ws->Wih_lo : ws->Wih_hi)
            + (size_t)((nb*8 + ntl)*80 + 16 + kc)*512 + lane*8;
        gll16(src, &sm[buf][(8+tt)*512]);
      }
    } else {
      #pragma unroll
      for (int j=0;j<2;j++){
        int tt = wid*2 + j;
        const bf16* src = ws->Wenc_hi
            + (size_t)(((nb-16)*8 + tt)*64 + kc)*512 + lane*8;
        gll16(src, &sm[buf][(8+tt)*512]);
      }
    }
  };
  auto cvtwr = [&](int buf, float4 v0, float4 v1){
    float v[8] = {v0.x,v0.y,v0.z,v0.w,v1.x,v1.y,v1.z,v1.w};
    bf16x8 hv, lv;
    #pragma unroll
    for (int j=0;j<8;j++){ bf16 h=(bf16)v[j]; hv[j]=h; lv[j]=(bf16)(v[j]-(float)h); }
    *(bf16x8*)(&sm[buf][a_ds]) = hv;
    *(bf16x8*)(&sm[buf][a_ds+512]) = lv;
  };

  stageB(0, 0);
  { float4 v0 = *(const float4*)arow;
    float4 v1 = *(const float4*)(arow+4);
    cvtwr(0, v0, v1); }
  __syncthreads();

  for (int kc=0; kc<64; kc++){
    int cur = kc & 1;
    bool pf = (kc < 63);
    float4 v0, v1;
    if (pf){
      stageB(kc+1, cur^1);
      const float* p = arow + (kc+1)*32;
      v0 = *(const float4*)p; v1 = *(const float4*)(p+4);
    }
    const bf16* S = sm[cur];
    bf16x8 ah = ldb8(S + (wid*2)*512 + lane*8);
    bf16x8 al = ldb8(S + (wid*2+1)*512 + lane*8);
    if (is_fg){
      #pragma unroll
      for (int u=0;u<8;u++){
        bf16x8 wh = ldb8(S + (size_t)(8+u*2)*512 + lane*8);
        bf16x8 wl = ldb8(S + (size_t)(9+u*2)*512 + lane*8);
        acc[u] = mfma16(ah, wh, acc[u]);
        acc[u] = mfma16(al, wh, acc[u]);
        acc[u] = mfma16(ah, wl, acc[u]);
      }
    } else {
      #pragma unroll
      for (int u=0;u<8;u++){
        bf16x8 wh = ldb8(S + (size_t)(8+u)*512 + lane*8);
        acc[u] = mfma16(ah, wh, acc[u]);
        acc[u] = mfma16(al, wh, acc[u]);
      }
    }
    if (pf) cvtwr(cur^1, v0, v1);
    __syncthreads();
  }

  if (is_fg){
    #pragma unroll
    for (int u=0;u<8;u++){
      int col = nb*128 + u*16 + lane15;
      #pragma unroll
      for (int r=0;r<4;r++){
        int row = mb*64 + wid*16 + quad*4 + r;
        ws->u.fg16[(size_t)row*(4*HH) + col] = (f16)acc[u][r];
      }
    }
  } else {
    #pragma unroll
    for (int u=0;u<8;u++){
      int col = (nb-16)*128 + u*16 + lane15;
      float bias = benc[col];
      #pragma unroll
      for (int r=0;r<4;r++){
        int row = mb*64 + wid*16 + quad*4 + r;
        ws->att1_16[(size_t)row*AAT + col] = (f16)(acc[u][r] + bias);
      }
    }
  }
}

// ---------------- step loop: producer/consumer via device-scope flags --------------
// grid = 208 x 256, all blocks resident (1/CU, LDS-bound). No grid.sync.
// Producers (blk<80): 2 waves each, col-tile ct=blk*2+wid of
//   hw[2560][64] = [Whh;Wdec](fp16 T16) @ h16t. Read Wcomb slice once/step.
// Consumers (blk>=80): (b, jhalf). fg16 half + att1(f16) pinned in LDS across all
//   steps. Per step: att2/hwhh from hw, e+softmax (redundant x2), gate-sum, LSTM.
__global__ __launch_bounds__(256) void k_steps(Wks* __restrict__ ws,
    const float* __restrict__ bdec, const float* __restrict__ Wfull,
    float* __restrict__ out)
{
  __shared__ __align__(16) f16 att1_s[NN*512];    // 50176 B
  __shared__ __align__(16) f16 fg_s[NN*1024];     // 100352 B, [n][g][256]
  __shared__ float att2_s[512];
  __shared__ float wf_s[512];
  __shared__ float bd_s[512];
  __shared__ float g_s[4*256];
  __shared__ float e_s[64];
  __shared__ float al_s[64];
  int blk = blockIdx.x;
  int tid = threadIdx.x;
  int lane = tid & 63, wid = tid >> 6;

  if (blk < NPROD){
    for (int t=0; t<NSTEP; t++){
      if (tid==0 && t>0){
        while (__hip_atomic_load(&ws->flagH, __ATOMIC_ACQUIRE,
                                 __HIP_MEMORY_SCOPE_AGENT) < (unsigned)(NCONS*t))
          __builtin_amdgcn_s_sleep(2);
      }
      __syncthreads();
      if (wid < 2){
        int ct = blk*2 + wid;                 // 0..159
        f32x4 acc[4] = {};
        for (int kc=0; kc<16; kc++){
          f16x8 wv = *(const f16x8*)(ws->Wcomb16 + (((size_t)ct*16 + kc)*64 + lane)*8);
          #pragma unroll
          for (int rt=0;rt<4;rt++){
            f16x8 hv = *(const f16x8*)(ws->h16t + (((size_t)rt*16 + kc)*64 + lane)*8);
            acc[rt] = mfma16f(hv, wv, acc[rt]);
          }
        }
        int col = ct*16 + (lane&15), quad = lane>>4;
        #pragma unroll
        for (int rt=0;rt<4;rt++){
          #pragma unroll
          for (int r=0;r<4;r++)
            ws->hw[(size_t)col*64 + rt*16 + quad*4 + r] = acc[rt][r];
        }
      }
      __syncthreads();
      if (tid==0)
        __hip_atomic_fetch_add(&ws->flagP, 1u, __ATOMIC_RELEASE,
                               __HIP_MEMORY_SCOPE_AGENT);
    }
    return;
  }

  // ---------------- consumer ----------------
  int cb = blk - NPROD;
  int b = cb >> 1, jh = cb & 1;
  for (int i = tid; i < NN*64; i += 256)
    *(f16x8*)(att1_s + (size_t)i*8) =
        *(const f16x8*)(ws->att1_16 + ((size_t)b*NN*64 + i)*8);
  for (int i = tid; i < NN*4*32; i += 256){
    int n = i >> 7, rem = i & 127, g2 = rem >> 5, c8 = rem & 31;
    *(f16x8*)(fg_s + (((n<<2) + g2)<<8) + c8*8) =
        *(const f16x8*)(ws->u.fg16 + (size_t)(b*NN+n)*2048 + g2*512 + jh*256 + c8*8);
  }
  wf_s[tid] = Wfull[tid]; wf_s[tid+256] = Wfull[tid+256];
  bd_s[tid] = bdec[tid];  bd_s[tid+256] = bdec[tid+256];
  float c_reg = ws->c0[b*HH + jh*256 + tid];
  int g = tid>>6, i4 = (tid&63)*4;
  int col = jh*256 + tid;
  int kc = col>>5, lane_w = ((col&31)>>3)*16 + (b&15), j8 = col&7;
  int offh = (((b>>4)*16 + kc)*64 + lane_w)*8 + j8;
  __syncthreads();

  for (int t=0; t<NSTEP; t++){
    if (tid==0){
      while (__hip_atomic_load(&ws->flagP, __ATOMIC_ACQUIRE,
                               __HIP_MEMORY_SCOPE_AGENT) < (unsigned)(NPROD*(t+1)))
        __builtin_amdgcn_s_sleep(2);
    }
    __syncthreads();
    att2_s[tid]     = ws->hw[(size_t)(2048+tid)*64 + b]     + bd_s[tid];
    att2_s[tid+256] = ws->hw[(size_t)(2048+256+tid)*64 + b] + bd_s[tid+256];
    float4 gacc;
    {
      int gc = g*512 + jh*256 + i4;
      float4 ev = *(const float4*)(ws->embg + (size_t)(t*64+b)*2048 + gc);
      gacc.x = ev.x + ws->hw[(size_t)(gc+0)*64 + b];
      gacc.y = ev.y + ws->hw[(size_t)(gc+1)*64 + b];
      gacc.z = ev.z + ws->hw[(size_t)(gc+2)*64 + b];
      gacc.w = ev.w + ws->hw[(size_t)(gc+3)*64 + b];
    }
    __syncthreads();
    // e[n] = relu(att1 + att2) . wf
    for (int n = wid; n < NN; n += 4){
      f16x8 a1v = *(const f16x8*)(att1_s + n*512 + lane*8);
      float s = 0.f;
      #pragma unroll
      for (int j=0;j<8;j++){
        float v = (float)a1v[j] + att2_s[lane*8+j];
        v = fmaxf(v, 0.f);
        s += v * wf_s[lane*8+j];
      }
      #pragma unroll
      for (int off=32; off; off>>=1) s += __shfl_xor(s, off, 64);
      if (lane==0) e_s[n] = s;
    }
    __syncthreads();
    if (wid==0){
      float e = (lane < NN) ? e_s[lane] : -1e30f;
      float m = e;
      #pragma unroll
      for (int off=32; off; off>>=1) m = fmaxf(m, __shfl_xor(m, off, 64));
      float p = (lane < NN) ? expf(e - m) : 0.f;
      float su = p;
      #pragma unroll
      for (int off=32; off; off>>=1) su += __shfl_xor(su, off, 64);
      float al = p/su;
      if (lane < NN){
        al_s[lane] = al;
        if (jh==0) out[ALPHA_OFF + (size_t)(b*NSTEP + t)*NN + lane] = al;
      }
    }
    __syncthreads();
    // gate-sum from LDS-resident fg
    {
      const f16* fp_ = fg_s + (g<<8) + i4;
      #pragma unroll 7
      for (int n=0;n<NN;n++){
        float a = al_s[n];
        f16x4 v = *(const f16x4*)(fp_ + (size_t)n*1024);
        gacc.x += a*(float)v[0];
        gacc.y += a*(float)v[1];
        gacc.z += a*(float)v[2];
        gacc.w += a*(float)v[3];
      }
      *(float4*)(g_s + (g<<8) + i4) = gacc;
    }
    __syncthreads();
    // LSTM pointwise: thread owns h-col = jh*256+tid
    {
      float iv = g_s[tid], fv = g_s[256+tid], gv = g_s[512+tid], ov = g_s[768+tid];
      float cn = sigm(fv)*c_reg + sigm(iv)*tanhf(gv);
      float hn = sigm(ov)*tanhf(cn);
      c_reg = cn;
      ws->h16t[offh] = (f16)hn;
      bf16 hi_ = (bf16)hn;
      bf16 lo_ = (bf16)(hn - (float)hi_);
      size_t offhist = ((((size_t)t*4 + (b>>4))*16 + kc)*64 + lane_w)*8 + j8;
      ws->hist_hi[offhist] = hi_;
      ws->hist_lo[offhist] = lo_;
    }
    __syncthreads();
    if (tid==0)
      __hip_atomic_fetch_add(&ws->flagH, 1u, __ATOMIC_RELEASE,
                             __HIP_MEMORY_SCOPE_AGENT);
  }
}

// ---------------- final pred GEMM: [1600 x 10000] = hist @ Wfcn^T (T16) ------------
__global__ __launch_bounds__(256) void k_pred(Wks* __restrict__ ws,
    const float* __restrict__ bfcn, float* __restrict__ out)
{
  int wid = threadIdx.x>>6, lane = threadIdx.x&63;
  int mt = blockIdx.y*4 + wid;
  int nt = blockIdx.x;
  if (mt >= NSTEP) return;
  int lane15 = lane&15, quad = lane>>4;
  int n0 = nt*64;
  f32x4 acc[4][4] = {};
  for (int kc=0; kc<16; kc++){
    bf16x8 a_hi[4], a_lo[4], bw[4];
    #pragma unroll
    for (int i=0;i<4;i++){
      a_hi[i] = ldb8(ws->hist_hi + (((size_t)(mt*4+i)*16 + kc)*64 + lane)*8);
      a_lo[i] = ldb8(ws->hist_lo + (((size_t)(mt*4+i)*16 + kc)*64 + lane)*8);
    }
    #pragma unroll
    for (int u=0;u<4;u++)
      bw[u] = ldb8(ws->u.w.Wfcn_hi + (((size_t)(nt*4+u)*16 + kc)*64 + lane)*8);
    #pragma unroll
    for (int u=0;u<4;u++){
      #pragma unroll
      for (int i=0;i<4;i++){
        acc[u][i] = mfma16(a_hi[i], bw[u], acc[u][i]);
        acc[u][i] = mfma16(a_lo[i], bw[u], acc[u][i]);
      }
    }
  }
  #pragma unroll
  for (int u=0;u<4;u++){
    int vc = n0 + u*16 + lane15;
    if (vc < VV){
      float bias = bfcn[vc];
      #pragma unroll
      for (int i=0;i<4;i++){
        #pragma unroll
        for (int r=0;r<4;r++){
          int row = mt*64 + i*16 + quad*4 + r;   // row = s*64 + b
          int sstep = row >> 6, bidx = row & 63;
          out[(size_t)(bidx*NSTEP + sstep)*VV + vc] = acc[u][i][r] + bias;
        }
      }
    }
  }
}

extern "C" void kernel_launch(void* const* d_in, const int* in_sizes, int n_in,
                              void* d_out, int out_size, void* d_ws, size_t ws_size,
                              hipStream_t stream)
{
  const float* feat = (const float*)d_in[0];
  const int*   caps = (const int*)d_in[1];
  const float* emb  = (const float*)d_in[2];
  const float* Wih  = (const float*)d_in[3];
  const float* bih  = (const float*)d_in[4];
  const float* Whh  = (const float*)d_in[5];
  const float* bhh  = (const float*)d_in[6];
  const float* Wenc = (const float*)d_in[7];
  const float* benc = (const float*)d_in[8];
  const float* Wdec = (const float*)d_in[9];
  const float* bdec = (const float*)d_in[10];
  const float* Wfull= (const float*)d_in[11];
  const float* bfull= (const float*)d_in[12];
  const float* Winh = (const float*)d_in[13];
  const float* binh = (const float*)d_in[14];
  const float* Winc = (const float*)d_in[15];
  const float* binc = (const float*)d_in[16];
  const float* Wfcn = (const float*)d_in[17];
  const float* bfcn = (const float*)d_in[18];
  float* out = (float*)d_out;
  Wks* ws = (Wks*)d_ws;
  if (ws_size < sizeof(Wks)) return;
  (void)bfull;

  #define SW(src, hi, lo, R, K) do { int nt_ = ((R+15)/16)*((K)/32); \
    hipLaunchKernelGGL(k_cvt_sw, dim3((nt_*64+255)/256), dim3(256), 0, stream, \
        src, hi, lo, R, K, nt_); } while(0)
  SW(Wih,  ws->Wih_hi,  ws->Wih_lo,  2048, 2560);
  SW(Wenc, ws->Wenc_hi, (bf16*)nullptr, 512, 2048);
  SW(Winh, ws->u.w.Winh_hi, (bf16*)nullptr, 512, 2048);
  SW(Winc, ws->u.w.Winc_hi, (bf16*)nullptr, 512, 2048);
  // Wcomb16 fp16 T16: rows 0..2047 = Whh, rows 2048..2559 = Wdec
  hipLaunchKernelGGL(k_cvt_sw16, dim3((128*16*64+255)/256), dim3(256), 0, stream,
      Whh, ws->Wcomb16, 2048, 512, 128*16);
  hipLaunchKernelGGL(k_cvt_sw16, dim3((32*16*64+255)/256), dim3(256), 0, stream,
      Wdec, ws->Wcomb16 + (size_t)2048*512, 512, 512, 32*16);
  hipLaunchKernelGGL(k_emb, dim3(400), dim3(256), 0, stream, caps, emb, ws);
  hipLaunchKernelGGL(k_mean, dim3(512), dim3(256), 0, stream, feat, ws);
  hipLaunchKernelGGL(k_init, dim3(16), dim3(256), 0, stream, ws, binh, binc);
  hipLaunchKernelGGL(k_embg, dim3(800), dim3(256), 0, stream, ws, bih, bhh);
  hipLaunchKernelGGL(k_enc, dim3(980), dim3(256), 0, stream, feat, benc, ws);
  hipLaunchKernelGGL(k_steps, dim3(NPROD+NCONS), dim3(256), 0, stream,
      ws, bdec, Wfull, out);
  // fg16 dead now: reuse its space for the Wfcn swizzle, then pred
  SW(Wfcn, ws->u.w.Wfcn_hi, (bf16*)nullptr, 10000, 512);
  #undef SW
  hipLaunchKernelGGL(k_pred, dim3(157, 7), dim3(256), 0, stream, ws, bfcn, out);
}

// Round 5
// 1106.715 us; speedup vs baseline: 2.2296x; 1.6687x over previous
//
#include <hip/hip_runtime.h>
#include <hip/hip_bf16.h>
#include <math.h>

typedef __bf16 bf16;
typedef __bf16 bf16x4 __attribute__((ext_vector_type(4)));
typedef __bf16 bf16x8 __attribute__((ext_vector_type(8)));
typedef float f32x4 __attribute__((ext_vector_type(4)));
typedef _Float16 f16;
typedef _Float16 f16x4 __attribute__((ext_vector_type(4)));
typedef _Float16 f16x8 __attribute__((ext_vector_type(8)));

#define BB 64
#define NN 49
#define CENC 2048
#define SS 26
#define NSTEP 25
#define VV 10000
#define EE 512
#define HH 512
#define AAT 512
#define ALPHA_OFF (BB*NSTEP*VV)
#define NPROD 40
#define NCONS 128

// T16 swizzled layout for MFMA operands: matrix M[R x K] (R%16==0, K%32==0)
// element (r,k) at sw[((rt*KC + kc)*64 + lane)*8 + j]
//   rt=r/16, kc=k/32, lane=((k%32)/8)*16 + (r%16), j=k%8, KC=K/32

struct Wks {
  unsigned int flagP; unsigned int _p0[31];   // producers add 1/step (40/step)
  unsigned int flagH; unsigned int _p1[31];   // consumers add 1/step (128/step)
  f16  att1_16[BB*NN*AAT];          // fp16 row-major [3136][512], benc folded
  float c0[BB*HH];                  // initial cell state
  f16  h16t[BB*HH];                 // h state, fp16 T16 (R=64,K=512,KC=16)
  float hw[BB*2560];                // producer out [b][col]: 0..2047 hwhh, 2048.. att2(raw)
  float embg[NSTEP*BB*4*HH];        // xemb @ Wih_e^T + bih + bhh  [1600][2048]
  union {                           // fg16 live k_enc..k_steps; w.* before/after
    f16 fg16[BB*NN*4*HH];           // feat @ Wih_c^T  [3136][2048] fp16
    struct {
      bf16 Wfcn_hi[10048*HH];       // T16 (R=10000 pad 10048,K=512) — after loop
      bf16 Winh_hi[HH*CENC];        // T16 (R=512,K=2048) — dead after k_init
      bf16 Winc_hi[HH*CENC];
    } w;
  } u;
  f16  Wcomb16[2560*HH];            // fp16 T16 (R=2560,K=512): rows 0..2047 Whh, 2048.. Wdec
  bf16 mean_hi[BB*CENC];            // T16 (R=64,K=2048)
  bf16 mean_lo[BB*CENC];
  bf16 xemb_hi[NSTEP*BB*EE];        // T16 (R=1600,K=512), row=s*64+b
  bf16 xemb_lo[NSTEP*BB*EE];
  bf16 hist_hi[NSTEP*BB*HH];        // T16 (R=1600,K=512), row=s*64+b
  bf16 hist_lo[NSTEP*BB*HH];
  bf16 Wih_hi[4*HH*(EE+CENC)];      // T16 (R=2048,K=2560,KC=80)
  bf16 Wih_lo[4*HH*(EE+CENC)];
  bf16 Wenc_hi[AAT*CENC];           // T16 (R=512,K=2048,KC=64)
};

__device__ inline bf16x8 ldb8(const bf16* p){ return *(const bf16x8*)p; }
__device__ inline f32x4 mfma16(bf16x8 a, bf16x8 b, f32x4 c){
  return __builtin_amdgcn_mfma_f32_16x16x32_bf16(a, b, c, 0, 0, 0);
}
__device__ inline f32x4 mfma16f(f16x8 a, f16x8 b, f32x4 c){
  return __builtin_amdgcn_mfma_f32_16x16x32_f16(a, b, c, 0, 0, 0);
}
__device__ inline float sigm(float x){ return 1.0f/(1.0f+expf(-x)); }

// relaxed spin (no per-poll L2 invalidate), then ONE acquire once satisfied
__device__ inline void wait_ge(unsigned int* f, unsigned int target){
  while (__hip_atomic_load(f, __ATOMIC_RELAXED, __HIP_MEMORY_SCOPE_AGENT) < target)
    __builtin_amdgcn_s_sleep(2);
  (void)__hip_atomic_load(f, __ATOMIC_ACQUIRE, __HIP_MEMORY_SCOPE_AGENT);
}

__device__ inline void split8(const float* p, bf16x8& hi, bf16x8& lo){
  float4 v0 = *(const float4*)p;
  float4 v1 = *(const float4*)(p+4);
  float v[8] = {v0.x,v0.y,v0.z,v0.w,v1.x,v1.y,v1.z,v1.w};
  #pragma unroll
  for (int j=0;j<8;j++){ bf16 h=(bf16)v[j]; hi[j]=h; lo[j]=(bf16)(v[j]-(float)h); }
}

// direct-to-LDS 16B per lane
__device__ inline void gll16(const bf16* g, bf16* l){
  __builtin_amdgcn_global_load_lds(
      (const __attribute__((address_space(1))) void*)g,
      (__attribute__((address_space(3))) void*)l, 16, 0, 0);
}

// ---------------- fp32 row-major -> T16 swizzle bf16 (hi + optional lo) ------------
__global__ __launch_bounds__(256) void k_cvt_sw(const float* __restrict__ src,
    bf16* __restrict__ hi, bf16* __restrict__ lo, int R, int K, int ntile){
  int g = blockIdx.x*256 + threadIdx.x;
  if (g >= ntile*64) return;
  int tile = g>>6, lane = g&63;
  int KC = K>>5;
  int rt = tile/KC, kc = tile - rt*KC;
  int r = rt*16 + (lane&15);
  if (r >= R) r = R-1;
  int k = kc*32 + (lane>>4)*8;
  bf16x8 hv, lv;
  split8(src + (size_t)r*K + k, hv, lv);
  *(bf16x8*)(hi + (size_t)g*8) = hv;
  if (lo) *(bf16x8*)(lo + (size_t)g*8) = lv;
}

// ---------------- fp32 row-major -> T16 swizzle fp16 -------------------------------
__global__ __launch_bounds__(256) void k_cvt_sw16(const float* __restrict__ src,
    f16* __restrict__ dst, int R, int K, int ntile){
  int g = blockIdx.x*256 + threadIdx.x;
  if (g >= ntile*64) return;
  int tile = g>>6, lane = g&63;
  int KC = K>>5;
  int rt = tile/KC, kc = tile - rt*KC;
  int r = rt*16 + (lane&15);
  if (r >= R) r = R-1;
  int k = kc*32 + (lane>>4)*8;
  float4 v0 = *(const float4*)(src + (size_t)r*K + k);
  float4 v1 = *(const float4*)(src + (size_t)r*K + k + 4);
  float v[8] = {v0.x,v0.y,v0.z,v0.w,v1.x,v1.y,v1.z,v1.w};
  f16x8 hv;
  #pragma unroll
  for (int j=0;j<8;j++) hv[j] = (f16)v[j];
  *(f16x8*)(dst + (size_t)g*8) = hv;
}

// ---------------- gather caption embeddings -> T16 hi/lo ---------------------------
__global__ __launch_bounds__(256) void k_emb(const int* __restrict__ caps,
    const float* __restrict__ emb, Wks* __restrict__ ws){
  int g = blockIdx.x*256 + threadIdx.x;
  if (g >= 1600*64) return;
  int tile = g>>6, lane = g&63;
  int rt = tile>>4, kc = tile&15;
  int r = rt*16 + (lane&15);
  int s = r>>6, b = r&63;
  int k = kc*32 + (lane>>4)*8;
  int cap = caps[b*SS + s];
  bf16x8 hv, lv;
  split8(emb + (size_t)cap*EE + k, hv, lv);
  *(bf16x8*)(ws->xemb_hi + (size_t)g*8) = hv;
  *(bf16x8*)(ws->xemb_lo + (size_t)g*8) = lv;
}

// ---------------- mean over N=49 pixels -> T16 hi/lo -------------------------------
__global__ __launch_bounds__(256) void k_mean(const float* __restrict__ feat, Wks* __restrict__ ws){
  int idx = blockIdx.x*256 + threadIdx.x;
  int b = idx >> 11, ch = idx & 2047;
  const float* p = feat + (size_t)b*NN*CENC + ch;
  float s = 0.f;
  #pragma unroll
  for (int n=0;n<NN;n++) s += p[n*CENC];
  s *= (1.0f/49.0f);
  bf16 hi = (bf16)s;
  int off = (((b>>4)*64 + (ch>>5))*64 + ((ch&31)>>3)*16 + (b&15))*8 + (ch&7);
  ws->mean_hi[off] = hi;
  ws->mean_lo[off] = (bf16)(s - (float)hi);
}

// ---------------- h0/c0 init (T16 operands); also zero flags -----------------------
__global__ __launch_bounds__(256) void k_init(Wks* __restrict__ ws,
    const float* __restrict__ bh, const float* __restrict__ bc){
  if (blockIdx.x == 0 && threadIdx.x == 0){ ws->flagP = 0u; ws->flagH = 0u; }
  int wid = threadIdx.x >> 6, lane = threadIdx.x & 63;
  int w = blockIdx.x*4 + wid;                // 0..63
  int mat = w >> 5, nt = w & 31;
  int lane15 = lane & 15, quad = lane >> 4;
  const bf16* Wm = mat ? ws->u.w.Winc_hi : ws->u.w.Winh_hi;
  const float* bm = mat ? bc : bh;
  int col = nt*16 + lane15;
  f32x4 acc[4] = {};
  for (int kc=0; kc<64; kc++){
    bf16x8 bfr = ldb8(Wm + (((size_t)nt*64 + kc)*64 + lane)*8);
    #pragma unroll
    for (int t=0;t<4;t++){
      acc[t] = mfma16(ldb8(ws->mean_hi + (((size_t)t*64 + kc)*64 + lane)*8), bfr, acc[t]);
      acc[t] = mfma16(ldb8(ws->mean_lo + (((size_t)t*64 + kc)*64 + lane)*8), bfr, acc[t]);
    }
  }
  float bias = bm[col];
  #pragma unroll
  for (int t=0;t<4;t++){
    #pragma unroll
    for (int r=0;r<4;r++){
      int b = t*16 + quad*4 + r;
      float v = acc[t][r] + bias;
      if (mat == 0){
        int kc2 = col>>5, lane_w = ((col&31)>>3)*16 + (b&15), j8 = col&7;
        ws->h16t[(((b>>4)*16 + kc2)*64 + lane_w)*8 + j8] = (f16)v;
      } else {
        ws->c0[b*HH + col] = v;
      }
    }
  }
}

// ---------------- embgates = xemb @ Wih_e^T + bih + bhh  [1600][2048] --------------
__global__ __launch_bounds__(256) void k_embg(Wks* __restrict__ ws,
    const float* __restrict__ bih, const float* __restrict__ bhh){
  int wid = threadIdx.x>>6, lane = threadIdx.x&63;
  int w = blockIdx.x*4 + wid;                // 3200 waves: w = nt*25 + mtg
  int nt = w/25, mtg = w - nt*25;
  int lane15 = lane&15, quad = lane>>4;
  f32x4 acc[4] = {};
  for (int kc=0; kc<16; kc++){
    bf16x8 wh = ldb8(ws->Wih_hi + (((size_t)nt*80 + kc)*64 + lane)*8);
    bf16x8 wl = ldb8(ws->Wih_lo + (((size_t)nt*80 + kc)*64 + lane)*8);
    #pragma unroll
    for (int i=0;i<4;i++){
      int rt = mtg*4 + i;
      bf16x8 ah = ldb8(ws->xemb_hi + (((size_t)rt*16 + kc)*64 + lane)*8);
      bf16x8 al = ldb8(ws->xemb_lo + (((size_t)rt*16 + kc)*64 + lane)*8);
      acc[i] = mfma16(ah, wh, acc[i]);
      acc[i] = mfma16(al, wh, acc[i]);
      acc[i] = mfma16(ah, wl, acc[i]);
    }
  }
  int col = nt*16 + lane15;
  float bias = bih[col] + bhh[col];
  #pragma unroll
  for (int i=0;i<4;i++){
    #pragma unroll
    for (int r=0;r<4;r++){
      int row = (mtg*4+i)*16 + quad*4 + r;   // row = s*64 + b
      ws->embg[(size_t)row*(4*HH) + col] = acc[i][r] + bias;
    }
  }
}

// ---------------- encoder GEMM: att1(f16) + featgates(f16) in one pass over feat ---
__global__ __launch_bounds__(256) void k_enc(const float* __restrict__ feat,
    const float* __restrict__ benc, Wks* __restrict__ ws)
{
  __shared__ bf16 sm[2][24*512];
  // bijective XCD swizzle over 980 wgs (q=122, r=4), mb-major within XCD chunk
  int xcd = blockIdx.x & 7, idx = blockIdx.x >> 3;
  int wg = (xcd < 4) ? xcd*123 + idx : 4*123 + (xcd-4)*122 + idx;
  int mb = wg / 20, nb = wg % 20;
  int tid = threadIdx.x, wid = tid>>6, lane = tid&63;
  int lane15 = lane&15, quad = lane>>4;
  bool is_fg = (nb < 16);
  int rr = tid>>2, qo = tid&3;
  const float* arow = feat + (size_t)(mb*64 + rr)*CENC + qo*8;
  int a_ds = ((rr>>4)*2)*512 + (qo*16 + (rr&15))*8;

  f32x4 acc[8] = {};

  auto stageB = [&](int kc, int buf){
    if (is_fg){
      #pragma unroll
      for (int j=0;j<4;j++){
        int tt = wid*4 + j;
        int ntl = tt>>1;
        const bf16* src = ((tt&1) ? ws->Wih_lo : ws->Wih_hi)
            + (size_t)((nb*8 + ntl)*80 + 16 + kc)*512 + lane*8;
        gll16(src, &sm[buf][(8+tt)*512]);
      }
    } else {
      #pragma unroll
      for (int j=0;j<2;j++){
        int tt = wid*2 + j;
        const bf16* src = ws->Wenc_hi
            + (size_t)(((nb-16)*8 + tt)*64 + kc)*512 + lane*8;
        gll16(src, &sm[buf][(8+tt)*512]);
      }
    }
  };
  auto cvtwr = [&](int buf, float4 v0, float4 v1){
    float v[8] = {v0.x,v0.y,v0.z,v0.w,v1.x,v1.y,v1.z,v1.w};
    bf16x8 hv, lv;
    #pragma unroll
    for (int j=0;j<8;j++){ bf16 h=(bf16)v[j]; hv[j]=h; lv[j]=(bf16)(v[j]-(float)h); }
    *(bf16x8*)(&sm[buf][a_ds]) = hv;
    *(bf16x8*)(&sm[buf][a_ds+512]) = lv;
  };

  stageB(0, 0);
  { float4 v0 = *(const float4*)arow;
    float4 v1 = *(const float4*)(arow+4);
    cvtwr(0, v0, v1); }
  __syncthreads();

  for (int kc=0; kc<64; kc++){
    int cur = kc & 1;
    bool pf = (kc < 63);
    float4 v0, v1;
    if (pf){
      stageB(kc+1, cur^1);
      const float* p = arow + (kc+1)*32;
      v0 = *(const float4*)p; v1 = *(const float4*)(p+4);
    }
    const bf16* S = sm[cur];
    bf16x8 ah = ldb8(S + (wid*2)*512 + lane*8);
    bf16x8 al = ldb8(S + (wid*2+1)*512 + lane*8);
    if (is_fg){
      #pragma unroll
      for (int u=0;u<8;u++){
        bf16x8 wh = ldb8(S + (size_t)(8+u*2)*512 + lane*8);
        bf16x8 wl = ldb8(S + (size_t)(9+u*2)*512 + lane*8);
        acc[u] = mfma16(ah, wh, acc[u]);
        acc[u] = mfma16(al, wh, acc[u]);
        acc[u] = mfma16(ah, wl, acc[u]);
      }
    } else {
      #pragma unroll
      for (int u=0;u<8;u++){
        bf16x8 wh = ldb8(S + (size_t)(8+u)*512 + lane*8);
        acc[u] = mfma16(ah, wh, acc[u]);
        acc[u] = mfma16(al, wh, acc[u]);
      }
    }
    if (pf) cvtwr(cur^1, v0, v1);
    __syncthreads();
  }

  if (is_fg){
    #pragma unroll
    for (int u=0;u<8;u++){
      int col = nb*128 + u*16 + lane15;
      #pragma unroll
      for (int r=0;r<4;r++){
        int row = mb*64 + wid*16 + quad*4 + r;
        ws->u.fg16[(size_t)row*(4*HH) + col] = (f16)acc[u][r];
      }
    }
  } else {
    #pragma unroll
    for (int u=0;u<8;u++){
      int col = (nb-16)*128 + u*16 + lane15;
      float bias = benc[col];
      #pragma unroll
      for (int r=0;r<4;r++){
        int row = mb*64 + wid*16 + quad*4 + r;
        ws->att1_16[(size_t)row*AAT + col] = (f16)(acc[u][r] + bias);
      }
    }
  }
}

// ---------------- step loop: producer/consumer via device-scope flags --------------
// grid = 168 x 256, all resident (1 block/CU via 157.5KB LDS). No grid.sync.
// Producers (blk<40): 4 waves, col-tiles ct=blk*4+wid of hw[b][2560] =
//   h @ [Whh;Wdec]^T. Wcomb16 slice pinned in LDS; h16t staged to LDS per step.
// Consumers (blk>=40): (b, jhalf). fg16 half + att1(f16) pinned in LDS across
//   steps. embg prefetched before the wait. Relaxed poll + single acquire.
__global__ __launch_bounds__(256) void k_steps(Wks* __restrict__ ws,
    const float* __restrict__ bdec, const float* __restrict__ Wfull,
    float* __restrict__ out)
{
  __shared__ __align__(16) unsigned char smem[161280];
  int blk = blockIdx.x;
  int tid = threadIdx.x;
  int lane = tid & 63, wid = tid >> 6;
  int lane15 = lane & 15, quad = lane >> 4;

  if (blk < NPROD){
    f16* h_s = (f16*)smem;                     // 64 KB
    f16* w_s = (f16*)(smem + 65536);           // 64 KB
    // pin this block's Wcomb16 slice (cols blk*64..blk*64+63) in LDS once
    const f16* wsrc = ws->Wcomb16 + (size_t)blk*32768;
    for (int i = tid; i < 4096; i += 256)
      *(f16x8*)(w_s + (size_t)i*8) = *(const f16x8*)(wsrc + (size_t)i*8);
    for (int t=0; t<NSTEP; t++){
      if (t>0 && tid==0) wait_ge(&ws->flagH, (unsigned)(NCONS*t));
      __syncthreads();
      // stage h16t (fresh each step) into LDS, coalesced
      for (int i = tid; i < 4096; i += 256)
        *(f16x8*)(h_s + (size_t)i*8) = *(const f16x8*)(ws->h16t + (size_t)i*8);
      __syncthreads();
      f32x4 acc[4] = {};
      for (int kc=0; kc<16; kc++){
        f16x8 wv = *(const f16x8*)(w_s + ((size_t)(wid*16 + kc)*64 + lane)*8);
        #pragma unroll
        for (int rt=0;rt<4;rt++){
          f16x8 hv = *(const f16x8*)(h_s + ((size_t)(rt*16 + kc)*64 + lane)*8);
          acc[rt] = mfma16f(hv, wv, acc[rt]);
        }
      }
      int col = blk*64 + wid*16 + lane15;
      #pragma unroll
      for (int rt=0;rt<4;rt++){
        #pragma unroll
        for (int r=0;r<4;r++)
          ws->hw[(size_t)(rt*16 + quad*4 + r)*2560 + col] = acc[rt][r];
      }
      __syncthreads();   // drain all waves' stores (vmcnt) before release
      if (tid==0)
        __hip_atomic_fetch_add(&ws->flagP, 1u, __ATOMIC_RELEASE,
                               __HIP_MEMORY_SCOPE_AGENT);
    }
    return;
  }

  // ---------------- consumer ----------------
  f16*   att1_s = (f16*)smem;                  // 50176 B
  f16*   fg_s   = (f16*)(smem + 50176);        // 100352 B
  float* att2_s = (float*)(smem + 150528);     // 2048 B
  float* wf_s   = (float*)(smem + 152576);     // 2048 B
  float* bd_s   = (float*)(smem + 154624);     // 2048 B
  float* g_s    = (float*)(smem + 156672);     // 4096 B
  float* e_s    = (float*)(smem + 160768);     // 256 B
  float* al_s   = (float*)(smem + 161024);     // 256 B
  int cb = blk - NPROD;
  int b = cb >> 1, jh = cb & 1;
  for (int i = tid; i < NN*64; i += 256)
    *(f16x8*)(att1_s + (size_t)i*8) =
        *(const f16x8*)(ws->att1_16 + ((size_t)b*NN*64 + i)*8);
  for (int i = tid; i < NN*4*32; i += 256){
    int n = i >> 7, rem = i & 127, g2 = rem >> 5, c8 = rem & 31;
    *(f16x8*)(fg_s + (((n<<2) + g2)<<8) + c8*8) =
        *(const f16x8*)(ws->u.fg16 + (size_t)(b*NN+n)*2048 + g2*512 + jh*256 + c8*8);
  }
  wf_s[tid] = Wfull[tid]; wf_s[tid+256] = Wfull[tid+256];
  bd_s[tid] = bdec[tid];  bd_s[tid+256] = bdec[tid+256];
  float c_reg = ws->c0[b*HH + jh*256 + tid];
  int g = tid>>6, i4 = (tid&63)*4;
  int gc = g*512 + jh*256 + i4;
  int col = jh*256 + tid;
  int kc = col>>5, lane_w = ((col&31)>>3)*16 + (b&15), j8 = col&7;
  int offh = (((b>>4)*16 + kc)*64 + lane_w)*8 + j8;
  __syncthreads();

  for (int t=0; t<NSTEP; t++){
    // prefetch embg slice (independent of producers) so latency hides under wait
    float4 ev = *(const float4*)(ws->embg + (size_t)(t*64+b)*2048 + gc);
    if (tid==0) wait_ge(&ws->flagP, (unsigned)(NPROD*(t+1)));
    __syncthreads();
    att2_s[tid]     = ws->hw[(size_t)b*2560 + 2048 + tid]       + bd_s[tid];
    att2_s[tid+256] = ws->hw[(size_t)b*2560 + 2048 + 256 + tid] + bd_s[tid+256];
    float4 gacc;
    {
      float4 hv4 = *(const float4*)(ws->hw + (size_t)b*2560 + gc);
      gacc.x = ev.x + hv4.x;
      gacc.y = ev.y + hv4.y;
      gacc.z = ev.z + hv4.z;
      gacc.w = ev.w + hv4.w;
    }
    __syncthreads();
    // e[n] = relu(att1 + att2) . wf
    for (int n = wid; n < NN; n += 4){
      f16x8 a1v = *(const f16x8*)(att1_s + n*512 + lane*8);
      float s = 0.f;
      #pragma unroll
      for (int j=0;j<8;j++){
        float v = (float)a1v[j] + att2_s[lane*8+j];
        v = fmaxf(v, 0.f);
        s += v * wf_s[lane*8+j];
      }
      #pragma unroll
      for (int off=32; off; off>>=1) s += __shfl_xor(s, off, 64);
      if (lane==0) e_s[n] = s;
    }
    __syncthreads();
    if (wid==0){
      float e = (lane < NN) ? e_s[lane] : -1e30f;
      float m = e;
      #pragma unroll
      for (int off=32; off; off>>=1) m = fmaxf(m, __shfl_xor(m, off, 64));
      float p = (lane < NN) ? expf(e - m) : 0.f;
      float su = p;
      #pragma unroll
      for (int off=32; off; off>>=1) su += __shfl_xor(su, off, 64);
      float al = p/su;
      if (lane < NN){
        al_s[lane] = al;
        if (jh==0) out[ALPHA_OFF + (size_t)(b*NSTEP + t)*NN + lane] = al;
      }
    }
    __syncthreads();
    // gate-sum from LDS-resident fg
    {
      const f16* fp_ = fg_s + (g<<8) + i4;
      #pragma unroll 7
      for (int n=0;n<NN;n++){
        float a = al_s[n];
        f16x4 v = *(const f16x4*)(fp_ + (size_t)n*1024);
        gacc.x += a*(float)v[0];
        gacc.y += a*(float)v[1];
        gacc.z += a*(float)v[2];
        gacc.w += a*(float)v[3];
      }
      *(float4*)(g_s + (g<<8) + i4) = gacc;
    }
    __syncthreads();
    // LSTM pointwise: thread owns h-col = jh*256+tid
    {
      float iv = g_s[tid], fv = g_s[256+tid], gv = g_s[512+tid], ov = g_s[768+tid];
      float cn = sigm(fv)*c_reg + sigm(iv)*tanhf(gv);
      float hn = sigm(ov)*tanhf(cn);
      c_reg = cn;
      ws->h16t[offh] = (f16)hn;
      bf16 hi_ = (bf16)hn;
      bf16 lo_ = (bf16)(hn - (float)hi_);
      size_t offhist = ((((size_t)t*4 + (b>>4))*16 + kc)*64 + lane_w)*8 + j8;
      ws->hist_hi[offhist] = hi_;
      ws->hist_lo[offhist] = lo_;
    }
    __syncthreads();   // drain stores before release
    if (tid==0)
      __hip_atomic_fetch_add(&ws->flagH, 1u, __ATOMIC_RELEASE,
                             __HIP_MEMORY_SCOPE_AGENT);
  }
}

// ---------------- final pred GEMM: [1600 x 10000] = hist @ Wfcn^T (T16) ------------
__global__ __launch_bounds__(256) void k_pred(Wks* __restrict__ ws,
    const float* __restrict__ bfcn, float* __restrict__ out)
{
  int wid = threadIdx.x>>6, lane = threadIdx.x&63;
  int mt = blockIdx.y*4 + wid;
  int nt = blockIdx.x;
  if (mt >= NSTEP) return;
  int lane15 = lane&15, quad = lane>>4;
  int n0 = nt*64;
  f32x4 acc[4][4] = {};
  for (int kc=0; kc<16; kc++){
    bf16x8 a_hi[4], a_lo[4], bw[4];
    #pragma unroll
    for (int i=0;i<4;i++){
      a_hi[i] = ldb8(ws->hist_hi + (((size_t)(mt*4+i)*16 + kc)*64 + lane)*8);
      a_lo[i] = ldb8(ws->hist_lo + (((size_t)(mt*4+i)*16 + kc)*64 + lane)*8);
    }
    #pragma unroll
    for (int u=0;u<4;u++)
      bw[u] = ldb8(ws->u.w.Wfcn_hi + (((size_t)(nt*4+u)*16 + kc)*64 + lane)*8);
    #pragma unroll
    for (int u=0;u<4;u++){
      #pragma unroll
      for (int i=0;i<4;i++){
        acc[u][i] = mfma16(a_hi[i], bw[u], acc[u][i]);
        acc[u][i] = mfma16(a_lo[i], bw[u], acc[u][i]);
      }
    }
  }
  #pragma unroll
  for (int u=0;u<4;u++){
    int vc = n0 + u*16 + lane15;
    if (vc < VV){
      float bias = bfcn[vc];
      #pragma unroll
      for (int i=0;i<4;i++){
        #pragma unroll
        for (int r=0;r<4;r++){
          int row = mt*64 + i*16 + quad*4 + r;   // row = s*64 + b
          int sstep = row >> 6, bidx = row & 63;
          out[(size_t)(bidx*NSTEP + sstep)*VV + vc] = acc[u][i][r] + bias;
        }
      }
    }
  }
}

extern "C" void kernel_launch(void* const* d_in, const int* in_sizes, int n_in,
                              void* d_out, int out_size, void* d_ws, size_t ws_size,
                              hipStream_t stream)
{
  const float* feat = (const float*)d_in[0];
  const int*   caps = (const int*)d_in[1];
  const float* emb  = (const float*)d_in[2];
  const float* Wih  = (const float*)d_in[3];
  const float* bih  = (const float*)d_in[4];
  const float* Whh  = (const float*)d_in[5];
  const float* bhh  = (const float*)d_in[6];
  const float* Wenc = (const float*)d_in[7];
  const float* benc = (const float*)d_in[8];
  const float* Wdec = (const float*)d_in[9];
  const float* bdec = (const float*)d_in[10];
  const float* Wfull= (const float*)d_in[11];
  const float* bfull= (const float*)d_in[12];
  const float* Winh = (const float*)d_in[13];
  const float* binh = (const float*)d_in[14];
  const float* Winc = (const float*)d_in[15];
  const float* binc = (const float*)d_in[16];
  const float* Wfcn = (const float*)d_in[17];
  const float* bfcn = (const float*)d_in[18];
  float* out = (float*)d_out;
  Wks* ws = (Wks*)d_ws;
  if (ws_size < sizeof(Wks)) return;
  (void)bfull;

  #define SW(src, hi, lo, R, K) do { int nt_ = ((R+15)/16)*((K)/32); \
    hipLaunchKernelGGL(k_cvt_sw, dim3((nt_*64+255)/256), dim3(256), 0, stream, \
        src, hi, lo, R, K, nt_); } while(0)
  SW(Wih,  ws->Wih_hi,  ws->Wih_lo,  2048, 2560);
  SW(Wenc, ws->Wenc_hi, (bf16*)nullptr, 512, 2048);
  SW(Winh, ws->u.w.Winh_hi, (bf16*)nullptr, 512, 2048);
  SW(Winc, ws->u.w.Winc_hi, (bf16*)nullptr, 512, 2048);
  // Wcomb16 fp16 T16: rows 0..2047 = Whh, rows 2048..2559 = Wdec
  hipLaunchKernelGGL(k_cvt_sw16, dim3((128*16*64+255)/256), dim3(256), 0, stream,
      Whh, ws->Wcomb16, 2048, 512, 128*16);
  hipLaunchKernelGGL(k_cvt_sw16, dim3((32*16*64+255)/256), dim3(256), 0, stream,
      Wdec, ws->Wcomb16 + (size_t)2048*512, 512, 512, 32*16);
  hipLaunchKernelGGL(k_emb, dim3(400), dim3(256), 0, stream, caps, emb, ws);
  hipLaunchKernelGGL(k_mean, dim3(512), dim3(256), 0, stream, feat, ws);
  hipLaunchKernelGGL(k_init, dim3(16), dim3(256), 0, stream, ws, binh, binc);
  hipLaunchKernelGGL(k_embg, dim3(800), dim3(256), 0, stream, ws, bih, bhh);
  hipLaunchKernelGGL(k_enc, dim3(980), dim3(256), 0, stream, feat, benc, ws);
  hipLaunchKernelGGL(k_steps, dim3(NPROD+NCONS), dim3(256), 0, stream,
      ws, bdec, Wfull, out);
  // fg16 dead now: reuse its space for the Wfcn swizzle, then pred
  SW(Wfcn, ws->u.w.Wfcn_hi, (bf16*)nullptr, 10000, 512);
  #undef SW
  hipLaunchKernelGGL(k_pred, dim3(157, 7), dim3(256), 0, stream, ws, bfcn, out);
}

// Round 6
// 933.356 us; speedup vs baseline: 2.6437x; 1.1857x over previous
//
#include <hip/hip_runtime.h>
#include <hip/hip_bf16.h>
#include <math.h>

typedef __bf16 bf16;
typedef __bf16 bf16x4 __attribute__((ext_vector_type(4)));
typedef __bf16 bf16x8 __attribute__((ext_vector_type(8)));
typedef float f32x4 __attribute__((ext_vector_type(4)));
typedef _Float16 f16;
typedef _Float16 f16x4 __attribute__((ext_vector_type(4)));
typedef _Float16 f16x8 __attribute__((ext_vector_type(8)));

#define BB 64
#define NN 49
#define CENC 2048
#define SS 26
#define NSTEP 25
#define VV 10000
#define EE 512
#define HH 512
#define AAT 512
#define ALPHA_OFF (BB*NSTEP*VV)
#define NPROD 40
#define NCONS 128

// T16 swizzled layout for MFMA operands: matrix M[R x K] (R%16==0, K%32==0)
// element (r,k) at sw[((rt*KC + kc)*64 + lane)*8 + j]
//   rt=r/16, kc=k/32, lane=((k%32)/8)*16 + (r%16), j=k%8, KC=K/32

struct Wks {
  unsigned int flagP; unsigned int _p0[31];   // producers add 1/step (40/step)
  unsigned int flagH; unsigned int _p1[31];   // consumers add 1/step (128/step)
  f16  att1_16[BB*NN*AAT];          // fp16 row-major [3136][512], benc folded
  float c0[BB*HH];                  // initial cell state
  f16  h16t[BB*HH];                 // h state, fp16 T16; cross-block via sc1 only
  float hw[BB*2560];                // producer out [b][col]; cross-block via sc1 only
  float embg[NSTEP*BB*4*HH];        // xemb @ Wih_e^T + bih + bhh  [1600][2048]
  union {                           // fg16 live k_enc..k_steps; w.* before/after
    f16 fg16[BB*NN*4*HH];           // feat @ Wih_c^T  [3136][2048] fp16
    struct {
      bf16 Wfcn_hi[10048*HH];       // T16 (R=10000 pad 10048,K=512) — after loop
      bf16 Winh_hi[HH*CENC];        // T16 (R=512,K=2048) — dead after k_init
      bf16 Winc_hi[HH*CENC];
    } w;
  } u;
  f16  Wcomb16[2560*HH];            // fp16 T16 (R=2560,K=512): rows 0..2047 Whh, 2048.. Wdec
  bf16 mean_hi[BB*CENC];            // T16 (R=64,K=2048)
  bf16 mean_lo[BB*CENC];
  bf16 xemb_hi[NSTEP*BB*EE];        // T16 (R=1600,K=512), row=s*64+b
  bf16 xemb_lo[NSTEP*BB*EE];
  bf16 hist_hi[NSTEP*BB*HH];        // T16 (R=1600,K=512), row=s*64+b
  bf16 hist_lo[NSTEP*BB*HH];
  bf16 Wih_hi[4*HH*(EE+CENC)];      // T16 (R=2048,K=2560,KC=80)
  bf16 Wih_lo[4*HH*(EE+CENC)];
  bf16 Wenc_hi[AAT*CENC];           // T16 (R=512,K=2048,KC=64)
};

__device__ inline bf16x8 ldb8(const bf16* p){ return *(const bf16x8*)p; }
__device__ inline f32x4 mfma16(bf16x8 a, bf16x8 b, f32x4 c){
  return __builtin_amdgcn_mfma_f32_16x16x32_bf16(a, b, c, 0, 0, 0);
}
__device__ inline f32x4 mfma16f(f16x8 a, f16x8 b, f32x4 c){
  return __builtin_amdgcn_mfma_f32_16x16x32_f16(a, b, c, 0, 0, 0);
}
__device__ inline float sigm(float x){ return 1.0f/(1.0f+expf(-x)); }

// relaxed spin only — NO acquire (no buffer_inv). Data moves via sc1 ops.
__device__ inline void wait_ge(unsigned int* f, unsigned int target){
  while (__hip_atomic_load(f, __ATOMIC_RELAXED, __HIP_MEMORY_SCOPE_AGENT) < target)
    __builtin_amdgcn_s_sleep(4);
}

// ---- LLC-direct (bypass L2) access helpers: issue, then vm_wait0() before use ----
__device__ inline float4 ld4_cv(const void* p){
  float4 r;
  asm volatile("global_load_dwordx4 %0, %1, off sc0 sc1" : "=v"(r) : "v"(p));
  return r;
}
__device__ inline float ld1_cv(const void* p){
  float r;
  asm volatile("global_load_dword %0, %1, off sc0 sc1" : "=v"(r) : "v"(p));
  return r;
}
__device__ inline void vm_wait0(){
  asm volatile("s_waitcnt vmcnt(0)" ::: "memory");
  __builtin_amdgcn_sched_barrier(0);
}
__device__ inline void st1_cv(void* p, float v){
  asm volatile("global_store_dword %0, %1, off sc0 sc1" :: "v"(p), "v"(v) : "memory");
}
__device__ inline void st2_cv(void* p, unsigned short v){
  unsigned v32 = v;
  asm volatile("global_store_short %0, %1, off sc0 sc1" :: "v"(p), "v"(v32) : "memory");
}

__device__ inline void split8(const float* p, bf16x8& hi, bf16x8& lo){
  float4 v0 = *(const float4*)p;
  float4 v1 = *(const float4*)(p+4);
  float v[8] = {v0.x,v0.y,v0.z,v0.w,v1.x,v1.y,v1.z,v1.w};
  #pragma unroll
  for (int j=0;j<8;j++){ bf16 h=(bf16)v[j]; hi[j]=h; lo[j]=(bf16)(v[j]-(float)h); }
}

// direct-to-LDS 16B per lane
__device__ inline void gll16(const bf16* g, bf16* l){
  __builtin_amdgcn_global_load_lds(
      (const __attribute__((address_space(1))) void*)g,
      (__attribute__((address_space(3))) void*)l, 16, 0, 0);
}

// ---------------- fp32 row-major -> T16 swizzle bf16 (hi + optional lo) ------------
__global__ __launch_bounds__(256) void k_cvt_sw(const float* __restrict__ src,
    bf16* __restrict__ hi, bf16* __restrict__ lo, int R, int K, int ntile){
  int g = blockIdx.x*256 + threadIdx.x;
  if (g >= ntile*64) return;
  int tile = g>>6, lane = g&63;
  int KC = K>>5;
  int rt = tile/KC, kc = tile - rt*KC;
  int r = rt*16 + (lane&15);
  if (r >= R) r = R-1;
  int k = kc*32 + (lane>>4)*8;
  bf16x8 hv, lv;
  split8(src + (size_t)r*K + k, hv, lv);
  *(bf16x8*)(hi + (size_t)g*8) = hv;
  if (lo) *(bf16x8*)(lo + (size_t)g*8) = lv;
}

// ---------------- fp32 row-major -> T16 swizzle fp16 -------------------------------
__global__ __launch_bounds__(256) void k_cvt_sw16(const float* __restrict__ src,
    f16* __restrict__ dst, int R, int K, int ntile){
  int g = blockIdx.x*256 + threadIdx.x;
  if (g >= ntile*64) return;
  int tile = g>>6, lane = g&63;
  int KC = K>>5;
  int rt = tile/KC, kc = tile - rt*KC;
  int r = rt*16 + (lane&15);
  if (r >= R) r = R-1;
  int k = kc*32 + (lane>>4)*8;
  float4 v0 = *(const float4*)(src + (size_t)r*K + k);
  float4 v1 = *(const float4*)(src + (size_t)r*K + k + 4);
  float v[8] = {v0.x,v0.y,v0.z,v0.w,v1.x,v1.y,v1.z,v1.w};
  f16x8 hv;
  #pragma unroll
  for (int j=0;j<8;j++) hv[j] = (f16)v[j];
  *(f16x8*)(dst + (size_t)g*8) = hv;
}

// ---------------- gather caption embeddings -> T16 hi/lo ---------------------------
__global__ __launch_bounds__(256) void k_emb(const int* __restrict__ caps,
    const float* __restrict__ emb, Wks* __restrict__ ws){
  int g = blockIdx.x*256 + threadIdx.x;
  if (g >= 1600*64) return;
  int tile = g>>6, lane = g&63;
  int rt = tile>>4, kc = tile&15;
  int r = rt*16 + (lane&15);
  int s = r>>6, b = r&63;
  int k = kc*32 + (lane>>4)*8;
  int cap = caps[b*SS + s];
  bf16x8 hv, lv;
  split8(emb + (size_t)cap*EE + k, hv, lv);
  *(bf16x8*)(ws->xemb_hi + (size_t)g*8) = hv;
  *(bf16x8*)(ws->xemb_lo + (size_t)g*8) = lv;
}

// ---------------- mean over N=49 pixels -> T16 hi/lo -------------------------------
__global__ __launch_bounds__(256) void k_mean(const float* __restrict__ feat, Wks* __restrict__ ws){
  int idx = blockIdx.x*256 + threadIdx.x;
  int b = idx >> 11, ch = idx & 2047;
  const float* p = feat + (size_t)b*NN*CENC + ch;
  float s = 0.f;
  #pragma unroll
  for (int n=0;n<NN;n++) s += p[n*CENC];
  s *= (1.0f/49.0f);
  bf16 hi = (bf16)s;
  int off = (((b>>4)*64 + (ch>>5))*64 + ((ch&31)>>3)*16 + (b&15))*8 + (ch&7);
  ws->mean_hi[off] = hi;
  ws->mean_lo[off] = (bf16)(s - (float)hi);
}

// ---------------- h0/c0 init (T16 operands); also zero flags -----------------------
__global__ __launch_bounds__(256) void k_init(Wks* __restrict__ ws,
    const float* __restrict__ bh, const float* __restrict__ bc){
  if (blockIdx.x == 0 && threadIdx.x == 0){ ws->flagP = 0u; ws->flagH = 0u; }
  int wid = threadIdx.x >> 6, lane = threadIdx.x & 63;
  int w = blockIdx.x*4 + wid;                // 0..63
  int mat = w >> 5, nt = w & 31;
  int lane15 = lane & 15, quad = lane >> 4;
  const bf16* Wm = mat ? ws->u.w.Winc_hi : ws->u.w.Winh_hi;
  const float* bm = mat ? bc : bh;
  int col = nt*16 + lane15;
  f32x4 acc[4] = {};
  for (int kc=0; kc<64; kc++){
    bf16x8 bfr = ldb8(Wm + (((size_t)nt*64 + kc)*64 + lane)*8);
    #pragma unroll
    for (int t=0;t<4;t++){
      acc[t] = mfma16(ldb8(ws->mean_hi + (((size_t)t*64 + kc)*64 + lane)*8), bfr, acc[t]);
      acc[t] = mfma16(ldb8(ws->mean_lo + (((size_t)t*64 + kc)*64 + lane)*8), bfr, acc[t]);
    }
  }
  float bias = bm[col];
  #pragma unroll
  for (int t=0;t<4;t++){
    #pragma unroll
    for (int r=0;r<4;r++){
      int b = t*16 + quad*4 + r;
      float v = acc[t][r] + bias;
      if (mat == 0){
        int kc2 = col>>5, lane_w = ((col&31)>>3)*16 + (b&15), j8 = col&7;
        ws->h16t[(((b>>4)*16 + kc2)*64 + lane_w)*8 + j8] = (f16)v;
      } else {
        ws->c0[b*HH + col] = v;
      }
    }
  }
}

// ---------------- embgates = xemb @ Wih_e^T + bih + bhh  [1600][2048] --------------
__global__ __launch_bounds__(256) void k_embg(Wks* __restrict__ ws,
    const float* __restrict__ bih, const float* __restrict__ bhh){
  int wid = threadIdx.x>>6, lane = threadIdx.x&63;
  int w = blockIdx.x*4 + wid;                // 3200 waves: w = nt*25 + mtg
  int nt = w/25, mtg = w - nt*25;
  int lane15 = lane&15, quad = lane>>4;
  f32x4 acc[4] = {};
  for (int kc=0; kc<16; kc++){
    bf16x8 wh = ldb8(ws->Wih_hi + (((size_t)nt*80 + kc)*64 + lane)*8);
    bf16x8 wl = ldb8(ws->Wih_lo + (((size_t)nt*80 + kc)*64 + lane)*8);
    #pragma unroll
    for (int i=0;i<4;i++){
      int rt = mtg*4 + i;
      bf16x8 ah = ldb8(ws->xemb_hi + (((size_t)rt*16 + kc)*64 + lane)*8);
      bf16x8 al = ldb8(ws->xemb_lo + (((size_t)rt*16 + kc)*64 + lane)*8);
      acc[i] = mfma16(ah, wh, acc[i]);
      acc[i] = mfma16(al, wh, acc[i]);
      acc[i] = mfma16(ah, wl, acc[i]);
    }
  }
  int col = nt*16 + lane15;
  float bias = bih[col] + bhh[col];
  #pragma unroll
  for (int i=0;i<4;i++){
    #pragma unroll
    for (int r=0;r<4;r++){
      int row = (mtg*4+i)*16 + quad*4 + r;   // row = s*64 + b
      ws->embg[(size_t)row*(4*HH) + col] = acc[i][r] + bias;
    }
  }
}

// ---------------- encoder GEMM: att1(f16) + featgates(f16) in one pass over feat ---
__global__ __launch_bounds__(256) void k_enc(const float* __restrict__ feat,
    const float* __restrict__ benc, Wks* __restrict__ ws)
{
  __shared__ bf16 sm[2][24*512];
  // bijective XCD swizzle over 980 wgs (q=122, r=4), mb-major within XCD chunk
  int xcd = blockIdx.x & 7, idx = blockIdx.x >> 3;
  int wg = (xcd < 4) ? xcd*123 + idx : 4*123 + (xcd-4)*122 + idx;
  int mb = wg / 20, nb = wg % 20;
  int tid = threadIdx.x, wid = tid>>6, lane = tid&63;
  int lane15 = lane&15, quad = lane>>4;
  bool is_fg = (nb < 16);
  int rr = tid>>2, qo = tid&3;
  const float* arow = feat + (size_t)(mb*64 + rr)*CENC + qo*8;
  int a_ds = ((rr>>4)*2)*512 + (qo*16 + (rr&15))*8;

  f32x4 acc[8] = {};

  auto stageB = [&](int kc, int buf){
    if (is_fg){
      #pragma unroll
      for (int j=0;j<4;j++){
        int tt = wid*4 + j;
        int ntl = tt>>1;
        const bf16* src = ((tt&1) ? ws->Wih_lo : ws->Wih_hi)
            + (size_t)((nb*8 + ntl)*80 + 16 + kc)*512 + lane*8;
        gll16(src, &sm[buf][(8+tt)*512]);
      }
    } else {
      #pragma unroll
      for (int j=0;j<2;j++){
        int tt = wid*2 + j;
        const bf16* src = ws->Wenc_hi
            + (size_t)(((nb-16)*8 + tt)*64 + kc)*512 + lane*8;
        gll16(src, &sm[buf][(8+tt)*512]);
      }
    }
  };
  auto cvtwr = [&](int buf, float4 v0, float4 v1){
    float v[8] = {v0.x,v0.y,v0.z,v0.w,v1.x,v1.y,v1.z,v1.w};
    bf16x8 hv, lv;
    #pragma unroll
    for (int j=0;j<8;j++){ bf16 h=(bf16)v[j]; hv[j]=h; lv[j]=(bf16)(v[j]-(float)h); }
    *(bf16x8*)(&sm[buf][a_ds]) = hv;
    *(bf16x8*)(&sm[buf][a_ds+512]) = lv;
  };

  stageB(0, 0);
  { float4 v0 = *(const float4*)arow;
    float4 v1 = *(const float4*)(arow+4);
    cvtwr(0, v0, v1); }
  __syncthreads();

  for (int kc=0; kc<64; kc++){
    int cur = kc & 1;
    bool pf = (kc < 63);
    float4 v0, v1;
    if (pf){
      stageB(kc+1, cur^1);
      const float* p = arow + (kc+1)*32;
      v0 = *(const float4*)p; v1 = *(const float4*)(p+4);
    }
    const bf16* S = sm[cur];
    bf16x8 ah = ldb8(S + (wid*2)*512 + lane*8);
    bf16x8 al = ldb8(S + (wid*2+1)*512 + lane*8);
    if (is_fg){
      #pragma unroll
      for (int u=0;u<8;u++){
        bf16x8 wh = ldb8(S + (size_t)(8+u*2)*512 + lane*8);
        bf16x8 wl = ldb8(S + (size_t)(9+u*2)*512 + lane*8);
        acc[u] = mfma16(ah, wh, acc[u]);
        acc[u] = mfma16(al, wh, acc[u]);
        acc[u] = mfma16(ah, wl, acc[u]);
      }
    } else {
      #pragma unroll
      for (int u=0;u<8;u++){
        bf16x8 wh = ldb8(S + (size_t)(8+u)*512 + lane*8);
        acc[u] = mfma16(ah, wh, acc[u]);
        acc[u] = mfma16(al, wh, acc[u]);
      }
    }
    if (pf) cvtwr(cur^1, v0, v1);
    __syncthreads();
  }

  if (is_fg){
    #pragma unroll
    for (int u=0;u<8;u++){
      int col = nb*128 + u*16 + lane15;
      #pragma unroll
      for (int r=0;r<4;r++){
        int row = mb*64 + wid*16 + quad*4 + r;
        ws->u.fg16[(size_t)row*(4*HH) + col] = (f16)acc[u][r];
      }
    }
  } else {
    #pragma unroll
    for (int u=0;u<8;u++){
      int col = (nb-16)*128 + u*16 + lane15;
      float bias = benc[col];
      #pragma unroll
      for (int r=0;r<4;r++){
        int row = mb*64 + wid*16 + quad*4 + r;
        ws->att1_16[(size_t)row*AAT + col] = (f16)(acc[u][r] + bias);
      }
    }
  }
}

// ---------------- step loop: producer/consumer, lock-free via LLC (sc1) ------------
// grid = 168 x 256, all resident (1 block/CU). No cache-maintenance ops in loop:
// h16t/hw move through LLC with sc0+sc1 loads/stores; flags are RELAXED atomics.
__global__ __launch_bounds__(256) void k_steps(Wks* __restrict__ ws,
    const float* __restrict__ bdec, const float* __restrict__ Wfull,
    float* __restrict__ out)
{
  __shared__ __align__(16) unsigned char smem[161280];
  int blk = blockIdx.x;
  int tid = threadIdx.x;
  int lane = tid & 63, wid = tid >> 6;
  int lane15 = lane & 15, quad = lane >> 4;

  if (blk < NPROD){
    f16* h_s = (f16*)smem;                     // 64 KB
    f16* w_s = (f16*)(smem + 65536);           // 64 KB
    // pin this block's Wcomb16 slice (cols blk*64..blk*64+63) in LDS once
    const f16* wsrc = ws->Wcomb16 + (size_t)blk*32768;
    for (int i = tid; i < 4096; i += 256)
      *(f16x8*)(w_s + (size_t)i*8) = *(const f16x8*)(wsrc + (size_t)i*8);
    for (int t=0; t<NSTEP; t++){
      if (t>0 && tid==0) wait_ge(&ws->flagH, (unsigned)(NCONS*t));
      __syncthreads();
      // stage h16t (fresh each step) LLC->LDS: batch-issue sc1 loads, wait once
      {
        float4 hbuf[16];
        #pragma unroll
        for (int i=0;i<16;i++)
          asm volatile("global_load_dwordx4 %0, %1, off sc0 sc1"
              : "=v"(hbuf[i])
              : "v"((const char*)ws->h16t + ((size_t)(tid + i*256))*16));
        asm volatile("s_waitcnt vmcnt(0)" ::: "memory");
        __builtin_amdgcn_sched_barrier(0);
        #pragma unroll
        for (int i=0;i<16;i++)
          *(float4*)((char*)h_s + ((size_t)(tid + i*256))*16) = hbuf[i];
      }
      __syncthreads();
      f32x4 acc[4] = {};
      for (int kc=0; kc<16; kc++){
        f16x8 wv = *(const f16x8*)(w_s + ((size_t)(wid*16 + kc)*64 + lane)*8);
        #pragma unroll
        for (int rt=0;rt<4;rt++){
          f16x8 hv = *(const f16x8*)(h_s + ((size_t)(rt*16 + kc)*64 + lane)*8);
          acc[rt] = mfma16f(hv, wv, acc[rt]);
        }
      }
      int col = blk*64 + wid*16 + lane15;
      #pragma unroll
      for (int rt=0;rt<4;rt++){
        #pragma unroll
        for (int r=0;r<4;r++)
          st1_cv(ws->hw + (size_t)(rt*16 + quad*4 + r)*2560 + col, acc[rt][r]);
      }
      __syncthreads();   // drains vmcnt (sc1 stores reached LLC) before release
      if (tid==0)
        __hip_atomic_fetch_add(&ws->flagP, 1u, __ATOMIC_RELAXED,
                               __HIP_MEMORY_SCOPE_AGENT);
    }
    return;
  }

  // ---------------- consumer ----------------
  f16*   att1_s = (f16*)smem;                  // 50176 B
  f16*   fg_s   = (f16*)(smem + 50176);        // 100352 B
  float* att2_s = (float*)(smem + 150528);     // 2048 B
  float* wf_s   = (float*)(smem + 152576);     // 2048 B
  float* bd_s   = (float*)(smem + 154624);     // 2048 B
  float* g_s    = (float*)(smem + 156672);     // 4096 B
  float* e_s    = (float*)(smem + 160768);     // 256 B
  float* al_s   = (float*)(smem + 161024);     // 256 B
  int cb = blk - NPROD;
  int b = cb >> 1, jh = cb & 1;
  for (int i = tid; i < NN*64; i += 256)
    *(f16x8*)(att1_s + (size_t)i*8) =
        *(const f16x8*)(ws->att1_16 + ((size_t)b*NN*64 + i)*8);
  for (int i = tid; i < NN*4*32; i += 256){
    int n = i >> 7, rem = i & 127, g2 = rem >> 5, c8 = rem & 31;
    *(f16x8*)(fg_s + (((n<<2) + g2)<<8) + c8*8) =
        *(const f16x8*)(ws->u.fg16 + (size_t)(b*NN+n)*2048 + g2*512 + jh*256 + c8*8);
  }
  wf_s[tid] = Wfull[tid]; wf_s[tid+256] = Wfull[tid+256];
  bd_s[tid] = bdec[tid];  bd_s[tid+256] = bdec[tid+256];
  float c_reg = ws->c0[b*HH + jh*256 + tid];
  int g = tid>>6, i4 = (tid&63)*4;
  int gc = g*512 + jh*256 + i4;
  int col = jh*256 + tid;
  int kc = col>>5, lane_w = ((col&31)>>3)*16 + (b&15), j8 = col&7;
  int offh = (((b>>4)*16 + kc)*64 + lane_w)*8 + j8;
  __syncthreads();

  for (int t=0; t<NSTEP; t++){
    // prefetch embg slice (independent of producers) so latency hides under wait
    float4 ev = *(const float4*)(ws->embg + (size_t)(t*64+b)*2048 + gc);
    if (tid==0) wait_ge(&ws->flagP, (unsigned)(NPROD*(t+1)));
    __syncthreads();
    // read hw via LLC (sc1): batch-issue, single wait
    float a2a = ld1_cv(ws->hw + (size_t)b*2560 + 2048 + tid);
    float a2b = ld1_cv(ws->hw + (size_t)b*2560 + 2048 + 256 + tid);
    float4 hv4 = ld4_cv(ws->hw + (size_t)b*2560 + gc);
    vm_wait0();
    att2_s[tid]     = a2a + bd_s[tid];
    att2_s[tid+256] = a2b + bd_s[tid+256];
    float4 gacc;
    gacc.x = ev.x + hv4.x;
    gacc.y = ev.y + hv4.y;
    gacc.z = ev.z + hv4.z;
    gacc.w = ev.w + hv4.w;
    __syncthreads();
    // e[n] = relu(att1 + att2) . wf
    for (int n = wid; n < NN; n += 4){
      f16x8 a1v = *(const f16x8*)(att1_s + n*512 + lane*8);
      float s = 0.f;
      #pragma unroll
      for (int j=0;j<8;j++){
        float v = (float)a1v[j] + att2_s[lane*8+j];
        v = fmaxf(v, 0.f);
        s += v * wf_s[lane*8+j];
      }
      #pragma unroll
      for (int off=32; off; off>>=1) s += __shfl_xor(s, off, 64);
      if (lane==0) e_s[n] = s;
    }
    __syncthreads();
    if (wid==0){
      float e = (lane < NN) ? e_s[lane] : -1e30f;
      float m = e;
      #pragma unroll
      for (int off=32; off; off>>=1) m = fmaxf(m, __shfl_xor(m, off, 64));
      float p = (lane < NN) ? expf(e - m) : 0.f;
      float su = p;
      #pragma unroll
      for (int off=32; off; off>>=1) su += __shfl_xor(su, off, 64);
      float al = p/su;
      if (lane < NN){
        al_s[lane] = al;
        if (jh==0) out[ALPHA_OFF + (size_t)(b*NSTEP + t)*NN + lane] = al;
      }
    }
    __syncthreads();
    // gate-sum from LDS-resident fg
    {
      const f16* fp_ = fg_s + (g<<8) + i4;
      #pragma unroll 7
      for (int n=0;n<NN;n++){
        float a = al_s[n];
        f16x4 v = *(const f16x4*)(fp_ + (size_t)n*1024);
        gacc.x += a*(float)v[0];
        gacc.y += a*(float)v[1];
        gacc.z += a*(float)v[2];
        gacc.w += a*(float)v[3];
      }
      *(float4*)(g_s + (g<<8) + i4) = gacc;
    }
    __syncthreads();
    // LSTM pointwise: thread owns h-col = jh*256+tid
    {
      float iv = g_s[tid], fv = g_s[256+tid], gv = g_s[512+tid], ov = g_s[768+tid];
      float cn = sigm(fv)*c_reg + sigm(iv)*tanhf(gv);
      float hn = sigm(ov)*tanhf(cn);
      c_reg = cn;
      f16 hf = (f16)hn;
      st2_cv(ws->h16t + offh, __builtin_bit_cast(unsigned short, hf));
      bf16 hi_ = (bf16)hn;
      bf16 lo_ = (bf16)(hn - (float)hi_);
      size_t offhist = ((((size_t)t*4 + (b>>4))*16 + kc)*64 + lane_w)*8 + j8;
      ws->hist_hi[offhist] = hi_;
      ws->hist_lo[offhist] = lo_;
    }
    __syncthreads();   // drains vmcnt (sc1 h stores at LLC) before release
    if (tid==0)
      __hip_atomic_fetch_add(&ws->flagH, 1u, __ATOMIC_RELAXED,
                             __HIP_MEMORY_SCOPE_AGENT);
  }
}

// ---------------- final pred GEMM: [1600 x 10000] = hist @ Wfcn^T (T16) ------------
__global__ __launch_bounds__(256) void k_pred(Wks* __restrict__ ws,
    const float* __restrict__ bfcn, float* __restrict__ out)
{
  int wid = threadIdx.x>>6, lane = threadIdx.x&63;
  int mt = blockIdx.y*4 + wid;
  int nt = blockIdx.x;
  if (mt >= NSTEP) return;
  int lane15 = lane&15, quad = lane>>4;
  int n0 = nt*64;
  f32x4 acc[4][4] = {};
  for (int kc=0; kc<16; kc++){
    bf16x8 a_hi[4], a_lo[4], bw[4];
    #pragma unroll
    for (int i=0;i<4;i++){
      a_hi[i] = ldb8(ws->hist_hi + (((size_t)(mt*4+i)*16 + kc)*64 + lane)*8);
      a_lo[i] = ldb8(ws->hist_lo + (((size_t)(mt*4+i)*16 + kc)*64 + lane)*8);
    }
    #pragma unroll
    for (int u=0;u<4;u++)
      bw[u] = ldb8(ws->u.w.Wfcn_hi + (((size_t)(nt*4+u)*16 + kc)*64 + lane)*8);
    #pragma unroll
    for (int u=0;u<4;u++){
      #pragma unroll
      for (int i=0;i<4;i++){
        acc[u][i] = mfma16(a_hi[i], bw[u], acc[u][i]);
        acc[u][i] = mfma16(a_lo[i], bw[u], acc[u][i]);
      }
    }
  }
  #pragma unroll
  for (int u=0;u<4;u++){
    int vc = n0 + u*16 + lane15;
    if (vc < VV){
      float bias = bfcn[vc];
      #pragma unroll
      for (int i=0;i<4;i++){
        #pragma unroll
        for (int r=0;r<4;r++){
          int row = mt*64 + i*16 + quad*4 + r;   // row = s*64 + b
          int sstep = row >> 6, bidx = row & 63;
          out[(size_t)(bidx*NSTEP + sstep)*VV + vc] = acc[u][i][r] + bias;
        }
      }
    }
  }
}

extern "C" void kernel_launch(void* const* d_in, const int* in_sizes, int n_in,
                              void* d_out, int out_size, void* d_ws, size_t ws_size,
                              hipStream_t stream)
{
  const float* feat = (const float*)d_in[0];
  const int*   caps = (const int*)d_in[1];
  const float* emb  = (const float*)d_in[2];
  const float* Wih  = (const float*)d_in[3];
  const float* bih  = (const float*)d_in[4];
  const float* Whh  = (const float*)d_in[5];
  const float* bhh  = (const float*)d_in[6];
  const float* Wenc = (const float*)d_in[7];
  const float* benc = (const float*)d_in[8];
  const float* Wdec = (const float*)d_in[9];
  const float* bdec = (const float*)d_in[10];
  const float* Wfull= (const float*)d_in[11];
  const float* bfull= (const float*)d_in[12];
  const float* Winh = (const float*)d_in[13];
  const float* binh = (const float*)d_in[14];
  const float* Winc = (const float*)d_in[15];
  const float* binc = (const float*)d_in[16];
  const float* Wfcn = (const float*)d_in[17];
  const float* bfcn = (const float*)d_in[18];
  float* out = (float*)d_out;
  Wks* ws = (Wks*)d_ws;
  if (ws_size < sizeof(Wks)) return;
  (void)bfull;

  #define SW(src, hi, lo, R, K) do { int nt_ = ((R+15)/16)*((K)/32); \
    hipLaunchKernelGGL(k_cvt_sw, dim3((nt_*64+255)/256), dim3(256), 0, stream, \
        src, hi, lo, R, K, nt_); } while(0)
  SW(Wih,  ws->Wih_hi,  ws->Wih_lo,  2048, 2560);
  SW(Wenc, ws->Wenc_hi, (bf16*)nullptr, 512, 2048);
  SW(Winh, ws->u.w.Winh_hi, (bf16*)nullptr, 512, 2048);
  SW(Winc, ws->u.w.Winc_hi, (bf16*)nullptr, 512, 2048);
  // Wcomb16 fp16 T16: rows 0..2047 = Whh, rows 2048..2559 = Wdec
  hipLaunchKernelGGL(k_cvt_sw16, dim3((128*16*64+255)/256), dim3(256), 0, stream,
      Whh, ws->Wcomb16, 2048, 512, 128*16);
  hipLaunchKernelGGL(k_cvt_sw16, dim3((32*16*64+255)/256), dim3(256), 0, stream,
      Wdec, ws->Wcomb16 + (size_t)2048*512, 512, 512, 32*16);
  hipLaunchKernelGGL(k_emb, dim3(400), dim3(256), 0, stream, caps, emb, ws);
  hipLaunchKernelGGL(k_mean, dim3(512), dim3(256), 0, stream, feat, ws);
  hipLaunchKernelGGL(k_init, dim3(16), dim3(256), 0, stream, ws, binh, binc);
  hipLaunchKernelGGL(k_embg, dim3(800), dim3(256), 0, stream, ws, bih, bhh);
  hipLaunchKernelGGL(k_enc, dim3(980), dim3(256), 0, stream, feat, benc, ws);
  hipLaunchKernelGGL(k_steps, dim3(NPROD+NCONS), dim3(256), 0, stream,
      ws, bdec, Wfull, out);
  // fg16 dead now: reuse its space for the Wfcn swizzle, then pred
  SW(Wfcn, ws->u.w.Wfcn_hi, (bf16*)nullptr, 10000, 512);
  #undef SW
  hipLaunchKernelGGL(k_pred, dim3(157, 7), dim3(256), 0, stream, ws, bfcn, out);
}